// Round 9
// baseline (957.062 us; speedup 1.0000x reference)
//
#include <hip/hip_runtime.h>

#define NN 20000
#define NE 200000
#define NG 512

__device__ __forceinline__ int lowerb(const int* a, int n, int v){
  int lo=0, hi=n;
  while(lo<hi){ int m=(lo+hi)>>1; if(a[m]<v) lo=m+1; else hi=m; }
  return lo;
}

// async global->LDS copy, 16B per lane. LDS dest must be linear in lane order
// (wave-uniform base + lane*16). AUX=2 sets NT (evict-first): H stream is single-use.
template<int AUX>
__device__ __forceinline__ void gload_lds16(const float4* g, float4* l){
  __builtin_amdgcn_global_load_lds(
    (const __attribute__((address_space(1))) void*)(g),
    (__attribute__((address_space(3))) void*)(l), 16, 0, AUX);
}

// ---------------- counting sort by tgt -> CSR ----------------
__global__ void k_count(const int* __restrict__ tgt, int* __restrict__ cnt){
  int e = blockIdx.x*blockDim.x + threadIdx.x;
  if(e<NE) atomicAdd(&cnt[tgt[e]], 1);
}

__global__ void k_scan(const int* __restrict__ cnt, int* __restrict__ row_start){
  __shared__ int part[1024];
  int t = threadIdx.x;
  const int CH = (NN + 1023)/1024; // 20
  int i0 = t*CH;
  int s = 0;
  for(int j=0;j<CH;j++){ int i=i0+j; if(i<NN) s += cnt[i]; }
  part[t] = s; __syncthreads();
  for(int d=1; d<1024; d<<=1){
    int v = (t>=d) ? part[t-d] : 0;
    __syncthreads();
    part[t] += v;
    __syncthreads();
  }
  int run = (t==0) ? 0 : part[t-1];
  for(int j=0;j<CH;j++){ int i=i0+j; if(i<NN){ row_start[i]=run; run += cnt[i]; } }
  if(t==0) row_start[NN] = part[1023];
}

// place edges in CSR order AND gather edge_attr to CSR order (fused)
__global__ void k_place(const int* __restrict__ src, const int* __restrict__ tgt,
                        const float* __restrict__ ea,
                        const int* __restrict__ row_start, int* __restrict__ cur,
                        int* __restrict__ es_src, float* __restrict__ es_ea){
  int e = blockIdx.x*blockDim.x + threadIdx.x;
  if(e>=NE) return;
  int n = tgt[e];
  int pos = row_start[n] + atomicAdd(&cur[n],1);
  es_src[pos] = src[e];
  const float4* s = (const float4*)ea + (size_t)e*4;
  float4* d = (float4*)es_ea + (size_t)pos*4;
  d[0]=s[0]; d[1]=s[1]; d[2]=s[2]; d[3]=s[3];
}

// ---------------- H = relu(es_ea @ W1 + b1), CSR-ordered, E x 128 ----------------
// Persistent grid-stride (round-8 win): dispatch turnover was capping occupancy.
// W1/b1 register tile hoisted out of the work loop.
__launch_bounds__(256, 4)
__global__ void k_hmlp(const float* __restrict__ es_ea, const float* __restrict__ W1,
                       const float* __restrict__ b1, float* __restrict__ H){
  const int pc = threadIdx.x & 31, er = threadIdx.x >> 5;
  float4 w1v[16];
  #pragma unroll
  for(int i=0;i<16;i++) w1v[i] = *(const float4*)&W1[i*128 + pc*4];
  const float4 bv = *(const float4*)&b1[pc*4];
  for(size_t e0 = (size_t)blockIdx.x*8; e0 < NE; e0 += (size_t)gridDim.x*8){
    const size_t e = e0 + er;
    float4 hv = bv;
    float eav[16];
    const float4* eap = (const float4*)(es_ea + e*16);
    #pragma unroll
    for(int q=0;q<4;q++){
      float4 v = eap[q];
      eav[q*4+0]=v.x; eav[q*4+1]=v.y; eav[q*4+2]=v.z; eav[q*4+3]=v.w;
    }
    #pragma unroll
    for(int i=0;i<16;i++){
      hv.x += eav[i]*w1v[i].x;
      hv.y += eav[i]*w1v[i].y;
      hv.z += eav[i]*w1v[i].z;
      hv.w += eav[i]*w1v[i].w;
    }
    hv.x = fmaxf(hv.x,0.f); hv.y = fmaxf(hv.y,0.f);
    hv.z = fmaxf(hv.z,0.f); hv.w = fmaxf(hv.w,0.f);
    *(float4*)&H[e*128 + pc*4] = hv;
  }
}

// ---------------- xbar[n,i] = mean over in-edges of x[src,i] ----------------
template<int IC>
__global__ void k_xbar(const float* __restrict__ x, const int* __restrict__ es_src,
                       const int* __restrict__ row_start, float* __restrict__ xbar){
  constexpr int TI = IC/16;
  const int wid = threadIdx.x>>6, lane = threadIdx.x&63;
  const int eg = lane>>4, ig = lane&15;
  for(int n0 = blockIdx.x*4; n0 < NN; n0 += gridDim.x*4){
    const int n = n0 + wid;
    const int a = row_start[n], b = row_start[n+1];
    float s[TI];
    #pragma unroll
    for(int u=0;u<TI;u++) s[u]=0.f;
    for(int e=a+eg; e<b; e+=4){
      int sn = es_src[e];
      #pragma unroll
      for(int u=0;u<TI;u++) s[u] += x[(size_t)sn*IC + ig*TI + u];
    }
    #pragma unroll
    for(int u=0;u<TI;u++){
      s[u] += __shfl_xor(s[u], 16, 64);
      s[u] += __shfl_xor(s[u], 32, 64);
    }
    if(eg==0){
      float dinv = 1.f/fmaxf((float)(b-a), 1.f);
      #pragma unroll
      for(int u=0;u<TI;u++) xbar[(size_t)n*IC + ig*TI + u] = s[u]*dinv;
    }
  }
}

// ---------------- fused NNConv layer: persistent + PF scatter + W2-ping-pong GEMM ----------------
// Round 9 = composition of individually-proven pieces:
//  - Persistent grid-stride items (round 8: occupancy 31->47 under otherwise-hurtful
//    changes; rounds 6/7 showed dispatch turnover caps short-block occupancy).
//  - BN=8 (round 7: BN=4 doubled W2 L2-traffic and ate the occupancy win).
//  - KS sized so LDS <= 24-33KB -> 4-6 blocks/CU eligible (L1 KS=2, L2 KS=8, L3 KS=4).
//  - PF scatter prefetch + W2 ping-pong RESTORED (round 8 dropped them: VALUBusy 63->48,
//    L2 layer 237->317us; round 2 proved ping-pong +11% VALUBusy at low occupancy).
//  - Dead-S cross-wave combine: one part slice per split (round-8-verified; WRITE 40->~10MB).
//  - NEVER __launch_bounds__ min-waves>3 (rounds 4/5: VGPR squeezed to 40, GB-scale spill).
// No-spill check: FETCH ~100-140MB, WRITE ~10-20MB, VGPR < 85.
template<int IC, int OC, int PLEN, int KS, int BN, int PP, int TI, int OQ, int TO, bool PF, int EB, int NB>
__launch_bounds__(256, 3)
__global__ void k_layer(const float* __restrict__ x_in, const float* __restrict__ H,
                        const int* __restrict__ es_src, const int* __restrict__ row_start,
                        const float* __restrict__ W2, float* __restrict__ part)
{
  constexpr int K    = PLEN*IC;
  constexpr int HV4  = PLEN/4;
  constexpr int XV   = IC/4;
  constexpr int NIW  = IC/TI;
  constexpr int NPW  = PLEN/PP;
  constexpr int G    = BN/4;
  constexpr int KQL  = 64/OQ;
  constexpr int TSPL = 4*KQL;
  constexpr int J    = (K/4)/TSPL;
  constexpr int NH4  = (EB*HV4 + 255)/256;   // hb staging chunks
  constexpr int NX4  = (EB*XV  + 255)/256;   // xs staging chunks
  constexpr int TOT  = (NN/BN)*KS;           // work items
  static_assert(NPW*NIW==64, "wave tile covers 64 lanes");
  static_assert(G*PP*TI <= 48, "spill-safe accumulator");
  static_assert(EB*(PLEN+IC) <= BN*K, "staging alias fits in S");
  static_assert((EB*HV4)%256==0, "hb tail must not round into xs region");
  static_assert(EB*PLEN/4 + NX4*256 <= BN*K/4, "xs tail rounding stays inside S");
  static_assert(OQ*TO==OC && (K/4)%TSPL==0, "gemm tiling");
  static_assert(J%2==0, "ping-pong needs even J");
  static_assert(3*BN*OC <= BN*K, "combine area fits in dead S");

  __shared__ __align__(16) float S[BN*K];
  __shared__ int rs_s[BN+1], ro[BN+1];

  float* hb = S;                 // EB*PLEN staged H slice
  float* xs = S + EB*PLEN;       // EB*IC staged x[src]

  const int tid = threadIdx.x;
  const int wid = tid>>6, lane = tid&63;
  const int pw = lane / NIW;
  const int iw = lane - pw*NIW;
  const int oq  = lane % OQ;
  const int kql = lane / OQ;
  const int o0  = oq*TO;

  const float4* H4 = (const float4*)H;
  const float4* x4 = (const float4*)x_in;

  #pragma unroll 1
  for(int it = blockIdx.x; it < TOT; it += NB){
    const int split = it % KS;
    const int nb = it / KS;
    const int n0 = nb*BN;
    const int p04 = split*HV4;

    if(tid<=BN) rs_s[tid] = row_start[n0+tid];
    __syncthreads();
    const int estart = rs_s[0], eend = rs_s[BN];

    float acc[G][PP][TI];
    #pragma unroll
    for(int g=0;g<G;g++)
      #pragma unroll
      for(int p=0;p<PP;p++)
        #pragma unroll
        for(int u=0;u<TI;u++) acc[g][p][u]=0.f;

    for(int bstart=estart; bstart<eend; bstart+=EB){
      const int ebc = min(EB, eend-bstart);
      if(tid<=BN){ int v = rs_s[tid]-bstart; ro[tid] = min(max(v,0), ebc); }
      const int hb_lim = ebc*HV4, xs_lim = ebc*XV;
      int sn_r[NX4];
      #pragma unroll
      for(int c=0;c<NX4;c++){
        int jc = min(tid + c*256, xs_lim-1);
        sn_r[c] = es_src[bstart + jc/XV];
      }
      #pragma unroll
      for(int c=0;c<NH4;c++){
        int j = tid + c*256;
        int jc = min(j, hb_lim-1);
        int e = jc/HV4, q = jc - e*HV4;
        gload_lds16<2>(H4 + (size_t)(bstart+e)*32 + p04 + q, ((float4*)hb) + j);
      }
      #pragma unroll
      for(int c=0;c<NX4;c++){
        int j = tid + c*256;
        int jc = min(j, xs_lim-1);
        int q = jc - (jc/XV)*XV;
        gload_lds16<0>(x4 + (size_t)sn_r[c]*XV + q, ((float4*)xs) + j);
      }
      __syncthreads();   // drains vmcnt (global_load_lds tracked there)
      // wave-private scatter, PF = software-pipelined edge loop (round-2/3-proven)
      if constexpr (PF){
        #pragma unroll
        for(int g=0; g<G; g++){
          const int nl = wid*G + g;
          const int a = ro[nl], b = ro[nl+1];
          if(a>=b) continue;
          float hv[PP], xv[TI];
          #pragma unroll
          for(int p=0;p<PP;p++) hv[p] = hb[a*PLEN + pw*PP + p];
          #pragma unroll
          for(int u=0;u<TI;u++) xv[u] = xs[a*IC + iw*TI + u];
          for(int e=a; e<b; e++){
            float hn[PP], xn[TI];
            if(e+1<b){
              #pragma unroll
              for(int p=0;p<PP;p++) hn[p] = hb[(e+1)*PLEN + pw*PP + p];
              #pragma unroll
              for(int u=0;u<TI;u++) xn[u] = xs[(e+1)*IC + iw*TI + u];
            }
            #pragma unroll
            for(int p=0;p<PP;p++)
              #pragma unroll
              for(int u=0;u<TI;u++) acc[g][p][u] += hv[p]*xv[u];
            #pragma unroll
            for(int p=0;p<PP;p++) hv[p]=hn[p];
            #pragma unroll
            for(int u=0;u<TI;u++) xv[u]=xn[u];
          }
        }
      } else {
        #pragma unroll
        for(int g=0; g<G; g++){
          const int nl = wid*G + g;
          const int a = ro[nl], b = ro[nl+1];
          for(int e=a; e<b; e++){
            float hv[PP];
            #pragma unroll
            for(int p=0;p<PP;p++) hv[p] = hb[e*PLEN + pw*PP + p];
            float xv[TI];
            #pragma unroll
            for(int u=0;u<TI;u++) xv[u] = xs[e*IC + iw*TI + u];
            #pragma unroll
            for(int p=0;p<PP;p++)
              #pragma unroll
              for(int u=0;u<TI;u++) acc[g][p][u] += hv[p]*xv[u];
          }
        }
      }
      __syncthreads();
    }

    // dump scaled S (staging area dead)
    #pragma unroll
    for(int g=0; g<G; g++){
      const int nl = wid*G + g;
      const float dv = 1.f/fmaxf((float)(rs_s[nl+1]-rs_s[nl]), 1.f);
      #pragma unroll
      for(int p=0;p<PP;p++)
        #pragma unroll
        for(int u=0;u<TI;u++)
          S[(nl*PLEN + pw*PP + p)*IC + iw*TI + u] = acc[g][p][u]*dv;
    }

    // ---- GEMM: k-split 4 waves x KQL lanes; coalesced W2; ping-pong W2 prefetch ----
    const float* W2b = W2 + (size_t)split*K*OC + o0;

    auto LOADW = [&](int j, float (&wv)[4][TO]){
      const int k4 = j*TSPL + wid*KQL + kql;
      #pragma unroll
      for(int r=0;r<4;r++){
        const float* wr = W2b + (size_t)(4*k4+r)*OC;
        if constexpr (TO==4){
          float4 a=*(const float4*)wr;
          wv[r][0]=a.x; wv[r][1]=a.y; wv[r][2]=a.z; wv[r][3]=a.w;
        } else if constexpr (TO==3){
          wv[r][0]=wr[0]; wv[r][1]=wr[1]; wv[r][2]=wr[2];
        } else {
          float2 a=*(const float2*)wr;
          wv[r][0]=a.x; wv[r][1]=a.y;
        }
      }
    };

    float outp[BN][TO];
    #pragma unroll
    for(int n=0;n<BN;n++)
      #pragma unroll
      for(int t=0;t<TO;t++) outp[n][t]=0.f;

    float wvA[4][TO], wvB[4][TO];
    LOADW(0, wvA);          // in flight across the barrier (independent of S)
    __syncthreads();        // S visible to all waves

    #pragma unroll 1
    for(int j=0;j<J;j+=2){
      LOADW(j+1, wvB);      // prefetch while FMAs on wvA run
      {
        const int k4 = j*TSPL + wid*KQL + kql;
        #pragma unroll
        for(int n=0;n<BN;n++){
          float4 sv = *(const float4*)&S[n*K + 4*k4];
          #pragma unroll
          for(int t=0;t<TO;t++)
            outp[n][t] += sv.x*wvA[0][t] + sv.y*wvA[1][t] + sv.z*wvA[2][t] + sv.w*wvA[3][t];
        }
      }
      if(j+2<J) LOADW(j+2, wvA);
      {
        const int k4 = (j+1)*TSPL + wid*KQL + kql;
        #pragma unroll
        for(int n=0;n<BN;n++){
          float4 sv = *(const float4*)&S[n*K + 4*k4];
          #pragma unroll
          for(int t=0;t<TO;t++)
            outp[n][t] += sv.x*wvB[0][t] + sv.y*wvB[1][t] + sv.z*wvB[2][t] + sv.w*wvB[3][t];
        }
      }
    }

    // intra-wave reduce over kql lanes
    #pragma unroll
    for(int m=OQ; m<64; m<<=1)
      #pragma unroll
      for(int n=0;n<BN;n++)
        #pragma unroll
        for(int t=0;t<TO;t++) outp[n][t] += __shfl_xor(outp[n][t], m, 64);

    // cross-wave combine through dead S: one part slice per split (round-8-verified)
    __syncthreads();   // all GEMM S-reads complete
    if(wid>0 && kql==0){
      #pragma unroll
      for(int n=0;n<BN;n++)
        #pragma unroll
        for(int t=0;t<TO;t++) S[((wid-1)*BN+n)*OC + o0 + t] = outp[n][t];
    }
    __syncthreads();
    if(wid==0 && kql==0){
      float* slice = part + (size_t)split*NN*OC;
      #pragma unroll
      for(int n=0;n<BN;n++){
        #pragma unroll
        for(int t=0;t<TO;t++){
          float v = outp[n][t];
          #pragma unroll
          for(int w2=0;w2<3;w2++) v += S[(w2*BN+n)*OC + o0 + t];
          outp[n][t] = v;
        }
        float* dst = slice + (size_t)(n0+n)*OC + o0;
        if constexpr (TO==4){
          *(float4*)dst = make_float4(outp[n][0],outp[n][1],outp[n][2],outp[n][3]);
        } else if constexpr (TO==3){
          dst[0]=outp[n][0]; dst[1]=outp[n][1]; dst[2]=outp[n][2];
        } else {
          *(float2*)dst = make_float2(outp[n][0],outp[n][1]);
        }
      }
    }
  }
}

// ---------------- epilogue: y = relu(sum_s part[s] + x@root + xbar@b2 + bias) ----------------
template<int IC, int OC, int SL>
__global__ void k_epi(const float* __restrict__ part, const float* __restrict__ x,
                      const float* __restrict__ xbar,
                      const float* __restrict__ root, const float* __restrict__ b2,
                      const float* __restrict__ bias, float* __restrict__ y)
{
  for(int idx = blockIdx.x*256 + threadIdx.x; idx < NN*OC; idx += gridDim.x*256){
    int n = idx/OC, o = idx - n*OC;
    float v = bias[o];
    #pragma unroll
    for(int s=0;s<SL;s++) v += part[(size_t)s*NN*OC + idx];
    #pragma unroll
    for(int i=0;i<IC;i++) v += x[(size_t)n*IC+i]*root[i*OC+o];
    #pragma unroll
    for(int i=0;i<IC;i++) v += xbar[(size_t)n*IC+i]*b2[i*OC+o];
    y[idx] = fmaxf(v, 0.f);
  }
}

// ---------------- set2set (2 steps) + final MLP, one wave per graph ----------------
__global__ void k_s2s(const float* __restrict__ xg, const int* __restrict__ batch,
  const float* __restrict__ Wih, const float* __restrict__ Whh,
  const float* __restrict__ bih, const float* __restrict__ bhh,
  const float* __restrict__ l1W, const float* __restrict__ l1b,
  const float* __restrict__ l2W, const float* __restrict__ l2b,
  const float* __restrict__ lfW, const float* __restrict__ lfb,
  float* __restrict__ out)
{
  int g = blockIdx.x, lane = threadIdx.x;
  __shared__ float hs[16], cs[16], qs[32], gs[64], rs[16];
  int r0 = lowerb(batch, NN, g);
  int r1 = lowerb(batch, NN, g+1);
  if(lane<16){ hs[lane]=0.f; cs[lane]=0.f; }
  if(lane<32) qs[lane]=0.f;
  __syncthreads();
  for(int step=0; step<2; step++){
    float gate = bih[lane] + bhh[lane];
    for(int k=0;k<32;k++) gate += qs[k]*Wih[lane*32+k];
    for(int k=0;k<16;k++) gate += hs[k]*Whh[lane*16+k];
    gs[lane] = gate;
    __syncthreads();
    if(lane<16){
      float ig = 1.f/(1.f+expf(-gs[lane]));
      float fg = 1.f/(1.f+expf(-gs[lane+16]));
      float gg = tanhf(gs[lane+32]);
      float og = 1.f/(1.f+expf(-gs[lane+48]));
      float cn = fg*cs[lane] + ig*gg;
      cs[lane] = cn;
      hs[lane] = og*tanhf(cn);
    }
    __syncthreads();
    float m = -1e30f;
    for(int n=r0+lane; n<r1; n+=64){
      float e=0.f;
      for(int k=0;k<16;k++) e += xg[n*16+k]*hs[k];
      m = fmaxf(m, e);
    }
    for(int d=1; d<64; d<<=1) m = fmaxf(m, __shfl_xor(m, d));
    float ssum = 0.f;
    float racc[16];
    #pragma unroll
    for(int k=0;k<16;k++) racc[k]=0.f;
    for(int n=r0+lane; n<r1; n+=64){
      float e=0.f, xv[16];
      #pragma unroll
      for(int k=0;k<16;k++){ xv[k]=xg[n*16+k]; e += xv[k]*hs[k]; }
      float a = expf(e - m);
      ssum += a;
      #pragma unroll
      for(int k=0;k<16;k++) racc[k] += a*xv[k];
    }
    for(int d=1; d<64; d<<=1) ssum += __shfl_xor(ssum, d);
    #pragma unroll
    for(int k=0;k<16;k++)
      for(int d=1; d<64; d<<=1) racc[k] += __shfl_xor(racc[k], d);
    ssum = fmaxf(ssum, 1e-16f);
    if(lane==0){
      #pragma unroll
      for(int k=0;k<16;k++) rs[k] = racc[k]/ssum;
    }
    __syncthreads();
    if(lane<16){ qs[lane]=hs[lane]; qs[16+lane]=rs[lane]; }
    __syncthreads();
  }
  if(lane<16){
    float v = l1b[lane];
    for(int k=0;k<32;k++) v += qs[k]*l1W[k*16+lane];
    gs[lane] = fmaxf(v,0.f);
  }
  __syncthreads();
  if(lane<8){
    float v = l2b[lane];
    for(int k=0;k<16;k++) v += gs[k]*l2W[k*8+lane];
    gs[32+lane] = fmaxf(v,0.f);
  }
  __syncthreads();
  if(lane==0){
    float v = lfb[0];
    for(int k=0;k<8;k++) v += gs[32+k]*lfW[k];
    out[g] = v;
  }
}

extern "C" void kernel_launch(void* const* d_in, const int* in_sizes, int n_in,
                              void* d_out, int out_size, void* d_ws, size_t ws_size,
                              hipStream_t stream) {
  const float* x0   = (const float*)d_in[0];
  const int*   ei   = (const int*)d_in[1];
  const float* ea   = (const float*)d_in[2];
  const int*   batch= (const int*)d_in[3];
  const float* c1W1 = (const float*)d_in[4];  const float* c1b1 = (const float*)d_in[5];
  const float* c1W2 = (const float*)d_in[6];  const float* c1b2 = (const float*)d_in[7];
  const float* c1rt = (const float*)d_in[8];  const float* c1bs = (const float*)d_in[9];
  const float* c2W1 = (const float*)d_in[10]; const float* c2b1 = (const float*)d_in[11];
  const float* c2W2 = (const float*)d_in[12]; const float* c2b2 = (const float*)d_in[13];
  const float* c2rt = (const float*)d_in[14]; const float* c2bs = (const float*)d_in[15];
  const float* c3W1 = (const float*)d_in[16]; const float* c3b1 = (const float*)d_in[17];
  const float* c3W2 = (const float*)d_in[18]; const float* c3b2 = (const float*)d_in[19];
  const float* c3rt = (const float*)d_in[20]; const float* c3bs = (const float*)d_in[21];
  const float* Wih  = (const float*)d_in[22]; const float* Whh  = (const float*)d_in[23];
  const float* bih  = (const float*)d_in[24]; const float* bhh  = (const float*)d_in[25];
  const float* l1W  = (const float*)d_in[26]; const float* l1b  = (const float*)d_in[27];
  const float* l2W  = (const float*)d_in[28]; const float* l2b  = (const float*)d_in[29];
  const float* lfW  = (const float*)d_in[30]; const float* lfb  = (const float*)d_in[31];
  float* out = (float*)d_out;

  const int* src = ei;
  const int* tgt = ei + NE;

  // workspace carve (~190 MB)
  char* w = (char*)d_ws;
  auto carve = [&](size_t bytes)->void*{ void* p = (void*)w; w += (bytes + 255) & ~(size_t)255; return p; };
  int*   row_start = (int*)carve((NN+1)*sizeof(int));
  int*   cur       = (int*)carve(NN*sizeof(int));
  int*   es_src    = (int*)carve(NE*sizeof(int));
  float* es_ea     = (float*)carve((size_t)NE*16*sizeof(float));
  float* Hbuf      = (float*)carve((size_t)NE*128*sizeof(float));
  float* xbar      = (float*)carve((size_t)NN*48*sizeof(float));
  float* y1   = (float*)carve((size_t)NN*48*sizeof(float));
  float* y2   = (float*)carve((size_t)NN*32*sizeof(float));
  float* y3   = (float*)carve((size_t)NN*16*sizeof(float));
  float* part = (float*)carve((size_t)16*NN*48*sizeof(float)); // up to 16 slices

  // ---- CSR by tgt (+ fused ea gather)
  hipMemsetAsync(cur, 0, NN*sizeof(int), stream);
  k_count<<<(NE+255)/256, 256, 0, stream>>>(tgt, cur);
  k_scan<<<1, 1024, 0, stream>>>(cur, row_start);
  hipMemsetAsync(cur, 0, NN*sizeof(int), stream);
  k_place<<<(NE+255)/256, 256, 0, stream>>>(src, tgt, ea, row_start, cur, es_src, es_ea);

  // ---- layer 1: IC=16 OC=48 | PLEN=64 KS=2 BN=8 PP=4 TI=4 | OQ=16 TO=3 | PF, EB=96, S=32KB, slices=2
  k_hmlp<<<2048, 256, 0, stream>>>(es_ea, c1W1, c1b1, Hbuf);
  k_xbar<16><<<2048, 256, 0, stream>>>(x0, es_src, row_start, xbar);
  k_layer<16,48,64,2,8,4,4,16,3,true,96,2048><<<2048, 256, 0, stream>>>(x0, Hbuf, es_src, row_start, c1W2, part);
  k_epi<16,48,2><<<2048, 256, 0, stream>>>(part, x0, xbar, c1rt, c1b2, c1bs, y1);

  // ---- layer 2: IC=48 OC=32 | PLEN=16 KS=8 BN=8 PP=4 TI=3 | OQ=8 TO=4 | PF, EB=64, S=24KB, slices=8
  k_hmlp<<<2048, 256, 0, stream>>>(es_ea, c2W1, c2b1, Hbuf);
  k_xbar<48><<<2048, 256, 0, stream>>>(y1, es_src, row_start, xbar);
  k_layer<48,32,16,8,8,4,3,8,4,true,64,2048><<<2048, 256, 0, stream>>>(y1, Hbuf, es_src, row_start, c2W2, part);
  k_epi<48,32,8><<<2048, 256, 0, stream>>>(part, y1, xbar, c2rt, c2b2, c2bs, y2);

  // ---- layer 3: IC=32 OC=16 | PLEN=32 KS=4 BN=8 PP=4 TI=4 | OQ=4 TO=4 | PF, EB=96, S=32KB, slices=4
  k_hmlp<<<2048, 256, 0, stream>>>(es_ea, c3W1, c3b1, Hbuf);
  k_xbar<32><<<2048, 256, 0, stream>>>(y2, es_src, row_start, xbar);
  k_layer<32,16,32,4,8,4,4,4,4,true,96,2048><<<2048, 256, 0, stream>>>(y2, Hbuf, es_src, row_start, c3W2, part);
  k_epi<32,16,4><<<2048, 256, 0, stream>>>(part, y2, xbar, c3rt, c3b2, c3bs, y3);

  // ---- set2set + MLP head
  k_s2s<<<NG, 64, 0, stream>>>(y3, batch, Wih, Whh, bih, bhh, l1W, l1b, l2W, l2b, lfW, lfb, out);
}

// Round 10
// 738.420 us; speedup vs baseline: 1.2961x; 1.2961x over previous
//
#include <hip/hip_runtime.h>

#define NN 20000
#define NE 200000
#define NG 512

__device__ __forceinline__ int lowerb(const int* a, int n, int v){
  int lo=0, hi=n;
  while(lo<hi){ int m=(lo+hi)>>1; if(a[m]<v) lo=m+1; else hi=m; }
  return lo;
}

// async global->LDS copy, 16B per lane. LDS dest must be linear in lane order
// (wave-uniform base + lane*16). AUX=2 sets NT (evict-first): H stream is single-use.
template<int AUX>
__device__ __forceinline__ void gload_lds16(const float4* g, float4* l){
  __builtin_amdgcn_global_load_lds(
    (const __attribute__((address_space(1))) void*)(g),
    (__attribute__((address_space(3))) void*)(l), 16, 0, AUX);
}

// ---------------- counting sort by tgt -> CSR ----------------
__global__ void k_count(const int* __restrict__ tgt, int* __restrict__ cnt){
  int e = blockIdx.x*blockDim.x + threadIdx.x;
  if(e<NE) atomicAdd(&cnt[tgt[e]], 1);
}

__global__ void k_scan(const int* __restrict__ cnt, int* __restrict__ row_start){
  __shared__ int part[1024];
  int t = threadIdx.x;
  const int CH = (NN + 1023)/1024; // 20
  int i0 = t*CH;
  int s = 0;
  for(int j=0;j<CH;j++){ int i=i0+j; if(i<NN) s += cnt[i]; }
  part[t] = s; __syncthreads();
  for(int d=1; d<1024; d<<=1){
    int v = (t>=d) ? part[t-d] : 0;
    __syncthreads();
    part[t] += v;
    __syncthreads();
  }
  int run = (t==0) ? 0 : part[t-1];
  for(int j=0;j<CH;j++){ int i=i0+j; if(i<NN){ row_start[i]=run; run += cnt[i]; } }
  if(t==0) row_start[NN] = part[1023];
}

// place edges in CSR order AND gather edge_attr to CSR order (fused)
__global__ void k_place(const int* __restrict__ src, const int* __restrict__ tgt,
                        const float* __restrict__ ea,
                        const int* __restrict__ row_start, int* __restrict__ cur,
                        int* __restrict__ es_src, float* __restrict__ es_ea){
  int e = blockIdx.x*blockDim.x + threadIdx.x;
  if(e>=NE) return;
  int n = tgt[e];
  int pos = row_start[n] + atomicAdd(&cur[n],1);
  es_src[pos] = src[e];
  const float4* s = (const float4*)ea + (size_t)e*4;
  float4* d = (float4*)es_ea + (size_t)pos*4;
  d[0]=s[0]; d[1]=s[1]; d[2]=s[2]; d[3]=s[3];
}

// ---------------- H = relu(es_ea @ W1 + b1), CSR-ordered, E x 128 ----------------
// Persistent grid-stride (round-8 aux win): W1/b1 register tile hoisted out of the
// work loop (was reloaded by each of 25000 short-lived blocks) + no dispatch turnover.
__launch_bounds__(256, 4)
__global__ void k_hmlp(const float* __restrict__ es_ea, const float* __restrict__ W1,
                       const float* __restrict__ b1, float* __restrict__ H){
  const int pc = threadIdx.x & 31, er = threadIdx.x >> 5;
  float4 w1v[16];
  #pragma unroll
  for(int i=0;i<16;i++) w1v[i] = *(const float4*)&W1[i*128 + pc*4];
  const float4 bv = *(const float4*)&b1[pc*4];
  for(size_t e0 = (size_t)blockIdx.x*8; e0 < NE; e0 += (size_t)gridDim.x*8){
    const size_t e = e0 + er;
    float4 hv = bv;
    float eav[16];
    const float4* eap = (const float4*)(es_ea + e*16);
    #pragma unroll
    for(int q=0;q<4;q++){
      float4 v = eap[q];
      eav[q*4+0]=v.x; eav[q*4+1]=v.y; eav[q*4+2]=v.z; eav[q*4+3]=v.w;
    }
    #pragma unroll
    for(int i=0;i<16;i++){
      hv.x += eav[i]*w1v[i].x;
      hv.y += eav[i]*w1v[i].y;
      hv.z += eav[i]*w1v[i].z;
      hv.w += eav[i]*w1v[i].w;
    }
    hv.x = fmaxf(hv.x,0.f); hv.y = fmaxf(hv.y,0.f);
    hv.z = fmaxf(hv.z,0.f); hv.w = fmaxf(hv.w,0.f);
    *(float4*)&H[e*128 + pc*4] = hv;
  }
}

// ---------------- xbar[n,i] = mean over in-edges of x[src,i] ----------------
// Persistent grid-stride (round-8 aux win).
template<int IC>
__global__ void k_xbar(const float* __restrict__ x, const int* __restrict__ es_src,
                       const int* __restrict__ row_start, float* __restrict__ xbar){
  constexpr int TI = IC/16;
  const int wid = threadIdx.x>>6, lane = threadIdx.x&63;
  const int eg = lane>>4, ig = lane&15;
  for(int n0 = blockIdx.x*4; n0 < NN; n0 += gridDim.x*4){
    const int n = n0 + wid;
    const int a = row_start[n], b = row_start[n+1];
    float s[TI];
    #pragma unroll
    for(int u=0;u<TI;u++) s[u]=0.f;
    for(int e=a+eg; e<b; e+=4){
      int sn = es_src[e];
      #pragma unroll
      for(int u=0;u<TI;u++) s[u] += x[(size_t)sn*IC + ig*TI + u];
    }
    #pragma unroll
    for(int u=0;u<TI;u++){
      s[u] += __shfl_xor(s[u], 16, 64);
      s[u] += __shfl_xor(s[u], 32, 64);
    }
    if(eg==0){
      float dinv = 1.f/fmaxf((float)(b-a), 1.f);
      #pragma unroll
      for(int u=0;u<TI;u++) xbar[(size_t)n*IC + ig*TI + u] = s[u]*dinv;
    }
  }
}

// ---------------- fused NNConv layer: wave-private scatter + coalesced k-split GEMM ----------------
// Round 10: EXACT round-3 layer (best measured: L2 237us, VGPR 68, no spill) -- five
// alternative layer structures (BN=4, 8-wave, persistent KS=8 with/without PF+pp)
// have now all measured worse. Only the aux kernels changed this round (round-8 win).
// Layer lessons baked in:
//  - PF scatter prefetch + W2-only ping-pong (round 2: +11% VALUBusy; round 8 removal:
//    VALUBusy 63->48, 237->317us). S reads stay in-iteration (round 1: dbuf of both
//    spilled -> FETCH 1.2GB).
//  - BN=8 for L1/L2 (round 7: BN=4 doubles W2 L2-traffic, eats any occupancy gain).
//  - NEVER __launch_bounds__ min-waves>3 (rounds 4/5: VGPR squeezed to 40, GB spill).
//  - VGPR must stay <= 68-ish; >64 caps 4 waves/SIMD (round 9: 84 VGPR -> 30% occ).
// No-spill check: FETCH ~85-101MB, WRITE 40MB, VGPR 68.
template<int IC, int OC, int PLEN, int KS, int BN, int PP, int TI, int OQ, int TO, bool PF, int EB>
__launch_bounds__(256, 3)
__global__ void k_layer(const float* __restrict__ x_in, const float* __restrict__ H,
                        const int* __restrict__ es_src, const int* __restrict__ row_start,
                        const float* __restrict__ W2, float* __restrict__ part)
{
  constexpr int K    = PLEN*IC;
  constexpr int HV4  = PLEN/4;
  constexpr int XV   = IC/4;
  constexpr int NIW  = IC/TI;
  constexpr int NPW  = PLEN/PP;
  constexpr int G    = BN/4;
  constexpr int KQL  = 64/OQ;
  constexpr int TSPL = 4*KQL;
  constexpr int J    = (K/4)/TSPL;
  constexpr int NH4  = (EB*HV4 + 255)/256;   // hb staging chunks
  constexpr int NX4  = (EB*XV  + 255)/256;   // xs staging chunks
  static_assert(NPW*NIW==64, "wave tile covers 64 lanes");
  static_assert(G*PP*TI <= 48, "spill-safe accumulator");
  static_assert(EB*(PLEN+IC) <= BN*K, "staging alias fits in S");
  static_assert((EB*HV4)%256==0, "hb tail must not round into xs region");
  static_assert(EB*PLEN/4 + NX4*256 <= BN*K/4, "xs tail rounding stays inside S");
  static_assert(OQ*TO==OC && (K/4)%TSPL==0, "gemm tiling");
  static_assert(J%2==0, "ping-pong needs even J");

  __shared__ __align__(16) float S[BN*K];
  __shared__ int rs_s[BN+1], ro[BN+1];

  float* hb = S;                 // EB*PLEN staged H slice
  float* xs = S + EB*PLEN;       // EB*IC staged x[src]

  const int tid = threadIdx.x;
  const int wid = tid>>6, lane = tid&63;
  const int split = blockIdx.x % KS;
  const int nb = blockIdx.x / KS;
  const int n0 = nb*BN;
  const int p04 = split*HV4;

  if(tid<=BN) rs_s[tid] = row_start[n0+tid];
  __syncthreads();
  const int estart = rs_s[0], eend = rs_s[BN];

  const int pw = lane / NIW;
  const int iw = lane - pw*NIW;

  float acc[G][PP][TI];
  #pragma unroll
  for(int g=0;g<G;g++)
    #pragma unroll
    for(int p=0;p<PP;p++)
      #pragma unroll
      for(int u=0;u<TI;u++) acc[g][p][u]=0.f;

  const float4* H4 = (const float4*)H;
  const float4* x4 = (const float4*)x_in;

  for(int bstart=estart; bstart<eend; bstart+=EB){
    const int ebc = min(EB, eend-bstart);
    if(tid<=BN){ int v = rs_s[tid]-bstart; ro[tid] = min(max(v,0), ebc); }
    const int hb_lim = ebc*HV4, xs_lim = ebc*XV;
    // pre-load gather indices (independent loads, issued together)
    int sn_r[NX4];
    #pragma unroll
    for(int c=0;c<NX4;c++){
      int jc = min(tid + c*256, xs_lim-1);
      sn_r[c] = es_src[bstart + jc/XV];
    }
    // async H slice -> hb (NT: single-use stream)
    #pragma unroll
    for(int c=0;c<NH4;c++){
      int j = tid + c*256;
      int jc = min(j, hb_lim-1);
      int e = jc/HV4, q = jc - e*HV4;
      gload_lds16<2>(H4 + (size_t)(bstart+e)*32 + p04 + q, ((float4*)hb) + j);
    }
    // async x[src] -> xs (temporal: reused across blocks)
    #pragma unroll
    for(int c=0;c<NX4;c++){
      int j = tid + c*256;
      int jc = min(j, xs_lim-1);
      int q = jc - (jc/XV)*XV;
      gload_lds16<0>(x4 + (size_t)sn_r[c]*XV + q, ((float4*)xs) + j);
    }
    __syncthreads();   // drains vmcnt (global_load_lds tracked there)
    // wave-private scatter (only the owning wave touches its nodes' edges)
    if constexpr (PF){
      #pragma unroll
      for(int g=0; g<G; g++){
        const int nl = wid*G + g;
        const int a = ro[nl], b = ro[nl+1];
        if(a>=b) continue;
        float hv[PP], xv[TI];
        #pragma unroll
        for(int p=0;p<PP;p++) hv[p] = hb[a*PLEN + pw*PP + p];
        #pragma unroll
        for(int u=0;u<TI;u++) xv[u] = xs[a*IC + iw*TI + u];
        for(int e=a; e<b; e++){
          float hn[PP], xn[TI];
          if(e+1<b){
            #pragma unroll
            for(int p=0;p<PP;p++) hn[p] = hb[(e+1)*PLEN + pw*PP + p];
            #pragma unroll
            for(int u=0;u<TI;u++) xn[u] = xs[(e+1)*IC + iw*TI + u];
          }
          #pragma unroll
          for(int p=0;p<PP;p++)
            #pragma unroll
            for(int u=0;u<TI;u++) acc[g][p][u] += hv[p]*xv[u];
          #pragma unroll
          for(int p=0;p<PP;p++) hv[p]=hn[p];
          #pragma unroll
          for(int u=0;u<TI;u++) xv[u]=xn[u];
        }
      }
    } else {
      #pragma unroll
      for(int g=0; g<G; g++){
        const int nl = wid*G + g;
        const int a = ro[nl], b = ro[nl+1];
        for(int e=a; e<b; e++){
          float hv[PP];
          #pragma unroll
          for(int p=0;p<PP;p++) hv[p] = hb[e*PLEN + pw*PP + p];
          float xv[TI];
          #pragma unroll
          for(int u=0;u<TI;u++) xv[u] = xs[e*IC + iw*TI + u];
          #pragma unroll
          for(int p=0;p<PP;p++)
            #pragma unroll
            for(int u=0;u<TI;u++) acc[g][p][u] += hv[p]*xv[u];
        }
      }
    }
    __syncthreads();
  }

  // dump scaled S (staging area dead)
  #pragma unroll
  for(int g=0; g<G; g++){
    const int nl = wid*G + g;
    const float dv = 1.f/fmaxf((float)(rs_s[nl+1]-rs_s[nl]), 1.f);
    #pragma unroll
    for(int p=0;p<PP;p++)
      #pragma unroll
      for(int u=0;u<TI;u++)
        S[(nl*PLEN + pw*PP + p)*IC + iw*TI + u] = acc[g][p][u]*dv;
  }

  // ---- GEMM: slice[n][o] partial over this wave's k-range; coalesced W2 ----
  const int oq  = lane % OQ;
  const int kql = lane / OQ;
  const int o0  = oq*TO;
  const float* W2b = W2 + (size_t)split*K*OC + o0;

  auto LOADW = [&](int j, float (&wv)[4][TO]){
    const int k4 = j*TSPL + wid*KQL + kql;
    #pragma unroll
    for(int r=0;r<4;r++){
      const float* wr = W2b + (size_t)(4*k4+r)*OC;
      if constexpr (TO==4){
        float4 a=*(const float4*)wr;
        wv[r][0]=a.x; wv[r][1]=a.y; wv[r][2]=a.z; wv[r][3]=a.w;
      } else if constexpr (TO==3){
        wv[r][0]=wr[0]; wv[r][1]=wr[1]; wv[r][2]=wr[2];
      } else {
        float2 a=*(const float2*)wr;
        wv[r][0]=a.x; wv[r][1]=a.y;
      }
    }
  };

  float outp[BN][TO];
  #pragma unroll
  for(int n=0;n<BN;n++)
    #pragma unroll
    for(int t=0;t<TO;t++) outp[n][t]=0.f;

  float wvA[4][TO], wvB[4][TO];
  LOADW(0, wvA);          // W2 j=0 in flight across the barrier (independent of S)
  __syncthreads();        // S visible to all waves

  #pragma unroll 1
  for(int j=0;j<J;j+=2){
    LOADW(j+1, wvB);      // prefetch while FMAs on wvA run
    {
      const int k4 = j*TSPL + wid*KQL + kql;
      #pragma unroll
      for(int n=0;n<BN;n++){
        float4 sv = *(const float4*)&S[n*K + 4*k4];
        #pragma unroll
        for(int t=0;t<TO;t++)
          outp[n][t] += sv.x*wvA[0][t] + sv.y*wvA[1][t] + sv.z*wvA[2][t] + sv.w*wvA[3][t];
      }
    }
    if(j+2<J) LOADW(j+2, wvA);   // prefetch while FMAs on wvB run
    {
      const int k4 = (j+1)*TSPL + wid*KQL + kql;
      #pragma unroll
      for(int n=0;n<BN;n++){
        float4 sv = *(const float4*)&S[n*K + 4*k4];
        #pragma unroll
        for(int t=0;t<TO;t++)
          outp[n][t] += sv.x*wvB[0][t] + sv.y*wvB[1][t] + sv.z*wvB[2][t] + sv.w*wvB[3][t];
      }
    }
  }

  // intra-wave reduce over kql lanes (masks OQ..32)
  #pragma unroll
  for(int m=OQ; m<64; m<<=1)
    #pragma unroll
    for(int n=0;n<BN;n++)
      #pragma unroll
      for(int t=0;t<TO;t++) outp[n][t] += __shfl_xor(outp[n][t], m, 64);

  if(kql==0){
    float* slice = part + (size_t)(split*4+wid)*NN*OC;
    #pragma unroll
    for(int n=0;n<BN;n++){
      float* dst = slice + (size_t)(n0+n)*OC + o0;
      if constexpr (TO==4){
        *(float4*)dst = make_float4(outp[n][0],outp[n][1],outp[n][2],outp[n][3]);
      } else if constexpr (TO==3){
        dst[0]=outp[n][0]; dst[1]=outp[n][1]; dst[2]=outp[n][2];
      } else {
        *(float2*)dst = make_float2(outp[n][0],outp[n][1]);
      }
    }
  }
}

// ---------------- epilogue: y = relu(sum_s part[s] + x@root + xbar@b2 + bias) ----------------
// Grid-stride (round-8 aux win).
template<int IC, int OC, int SL>
__global__ void k_epi(const float* __restrict__ part, const float* __restrict__ x,
                      const float* __restrict__ xbar,
                      const float* __restrict__ root, const float* __restrict__ b2,
                      const float* __restrict__ bias, float* __restrict__ y)
{
  for(int idx = blockIdx.x*256 + threadIdx.x; idx < NN*OC; idx += gridDim.x*256){
    int n = idx/OC, o = idx - n*OC;
    float v = bias[o];
    #pragma unroll
    for(int s=0;s<SL;s++) v += part[(size_t)s*NN*OC + idx];
    #pragma unroll
    for(int i=0;i<IC;i++) v += x[(size_t)n*IC+i]*root[i*OC+o];
    #pragma unroll
    for(int i=0;i<IC;i++) v += xbar[(size_t)n*IC+i]*b2[i*OC+o];
    y[idx] = fmaxf(v, 0.f);
  }
}

// ---------------- set2set (2 steps) + final MLP, one wave per graph ----------------
__global__ void k_s2s(const float* __restrict__ xg, const int* __restrict__ batch,
  const float* __restrict__ Wih, const float* __restrict__ Whh,
  const float* __restrict__ bih, const float* __restrict__ bhh,
  const float* __restrict__ l1W, const float* __restrict__ l1b,
  const float* __restrict__ l2W, const float* __restrict__ l2b,
  const float* __restrict__ lfW, const float* __restrict__ lfb,
  float* __restrict__ out)
{
  int g = blockIdx.x, lane = threadIdx.x;
  __shared__ float hs[16], cs[16], qs[32], gs[64], rs[16];
  int r0 = lowerb(batch, NN, g);
  int r1 = lowerb(batch, NN, g+1);
  if(lane<16){ hs[lane]=0.f; cs[lane]=0.f; }
  if(lane<32) qs[lane]=0.f;
  __syncthreads();
  for(int step=0; step<2; step++){
    float gate = bih[lane] + bhh[lane];
    for(int k=0;k<32;k++) gate += qs[k]*Wih[lane*32+k];
    for(int k=0;k<16;k++) gate += hs[k]*Whh[lane*16+k];
    gs[lane] = gate;
    __syncthreads();
    if(lane<16){
      float ig = 1.f/(1.f+expf(-gs[lane]));
      float fg = 1.f/(1.f+expf(-gs[lane+16]));
      float gg = tanhf(gs[lane+32]);
      float og = 1.f/(1.f+expf(-gs[lane+48]));
      float cn = fg*cs[lane] + ig*gg;
      cs[lane] = cn;
      hs[lane] = og*tanhf(cn);
    }
    __syncthreads();
    float m = -1e30f;
    for(int n=r0+lane; n<r1; n+=64){
      float e=0.f;
      for(int k=0;k<16;k++) e += xg[n*16+k]*hs[k];
      m = fmaxf(m, e);
    }
    for(int d=1; d<64; d<<=1) m = fmaxf(m, __shfl_xor(m, d));
    float ssum = 0.f;
    float racc[16];
    #pragma unroll
    for(int k=0;k<16;k++) racc[k]=0.f;
    for(int n=r0+lane; n<r1; n+=64){
      float e=0.f, xv[16];
      #pragma unroll
      for(int k=0;k<16;k++){ xv[k]=xg[n*16+k]; e += xv[k]*hs[k]; }
      float a = expf(e - m);
      ssum += a;
      #pragma unroll
      for(int k=0;k<16;k++) racc[k] += a*xv[k];
    }
    for(int d=1; d<64; d<<=1) ssum += __shfl_xor(ssum, d);
    #pragma unroll
    for(int k=0;k<16;k++)
      for(int d=1; d<64; d<<=1) racc[k] += __shfl_xor(racc[k], d);
    ssum = fmaxf(ssum, 1e-16f);
    if(lane==0){
      #pragma unroll
      for(int k=0;k<16;k++) rs[k] = racc[k]/ssum;
    }
    __syncthreads();
    if(lane<16){ qs[lane]=hs[lane]; qs[16+lane]=rs[lane]; }
    __syncthreads();
  }
  if(lane<16){
    float v = l1b[lane];
    for(int k=0;k<32;k++) v += qs[k]*l1W[k*16+lane];
    gs[lane] = fmaxf(v,0.f);
  }
  __syncthreads();
  if(lane<8){
    float v = l2b[lane];
    for(int k=0;k<16;k++) v += gs[k]*l2W[k*8+lane];
    gs[32+lane] = fmaxf(v,0.f);
  }
  __syncthreads();
  if(lane==0){
    float v = lfb[0];
    for(int k=0;k<8;k++) v += gs[32+k]*lfW[k];
    out[g] = v;
  }
}

extern "C" void kernel_launch(void* const* d_in, const int* in_sizes, int n_in,
                              void* d_out, int out_size, void* d_ws, size_t ws_size,
                              hipStream_t stream) {
  const float* x0   = (const float*)d_in[0];
  const int*   ei   = (const int*)d_in[1];
  const float* ea   = (const float*)d_in[2];
  const int*   batch= (const int*)d_in[3];
  const float* c1W1 = (const float*)d_in[4];  const float* c1b1 = (const float*)d_in[5];
  const float* c1W2 = (const float*)d_in[6];  const float* c1b2 = (const float*)d_in[7];
  const float* c1rt = (const float*)d_in[8];  const float* c1bs = (const float*)d_in[9];
  const float* c2W1 = (const float*)d_in[10]; const float* c2b1 = (const float*)d_in[11];
  const float* c2W2 = (const float*)d_in[12]; const float* c2b2 = (const float*)d_in[13];
  const float* c2rt = (const float*)d_in[14]; const float* c2bs = (const float*)d_in[15];
  const float* c3W1 = (const float*)d_in[16]; const float* c3b1 = (const float*)d_in[17];
  const float* c3W2 = (const float*)d_in[18]; const float* c3b2 = (const float*)d_in[19];
  const float* c3rt = (const float*)d_in[20]; const float* c3bs = (const float*)d_in[21];
  const float* Wih  = (const float*)d_in[22]; const float* Whh  = (const float*)d_in[23];
  const float* bih  = (const float*)d_in[24]; const float* bhh  = (const float*)d_in[25];
  const float* l1W  = (const float*)d_in[26]; const float* l1b  = (const float*)d_in[27];
  const float* l2W  = (const float*)d_in[28]; const float* l2b  = (const float*)d_in[29];
  const float* lfW  = (const float*)d_in[30]; const float* lfb  = (const float*)d_in[31];
  float* out = (float*)d_out;

  const int* src = ei;
  const int* tgt = ei + NE;

  // workspace carve (~190 MB)
  char* w = (char*)d_ws;
  auto carve = [&](size_t bytes)->void*{ void* p = (void*)w; w += (bytes + 255) & ~(size_t)255; return p; };
  int*   row_start = (int*)carve((NN+1)*sizeof(int));
  int*   cur       = (int*)carve(NN*sizeof(int));
  int*   es_src    = (int*)carve(NE*sizeof(int));
  float* es_ea     = (float*)carve((size_t)NE*16*sizeof(float));
  float* Hbuf      = (float*)carve((size_t)NE*128*sizeof(float));
  float* xbar      = (float*)carve((size_t)NN*48*sizeof(float));
  float* y1   = (float*)carve((size_t)NN*48*sizeof(float));
  float* y2   = (float*)carve((size_t)NN*32*sizeof(float));
  float* y3   = (float*)carve((size_t)NN*16*sizeof(float));
  float* part = (float*)carve((size_t)16*NN*48*sizeof(float)); // up to 16 slices

  // ---- CSR by tgt (+ fused ea gather)
  hipMemsetAsync(cur, 0, NN*sizeof(int), stream);
  k_count<<<(NE+255)/256, 256, 0, stream>>>(tgt, cur);
  k_scan<<<1, 1024, 0, stream>>>(cur, row_start);
  hipMemsetAsync(cur, 0, NN*sizeof(int), stream);
  k_place<<<(NE+255)/256, 256, 0, stream>>>(src, tgt, ea, row_start, cur, es_src, es_ea);

  // ---- layer 1: IC=16 OC=48 | PLEN=64 KS=2 BN=8 G=2 PP=4 TI=4 | OQ=16 TO=3 | PF on, EB=96 (8 slices)
  k_hmlp<<<2048, 256, 0, stream>>>(es_ea, c1W1, c1b1, Hbuf);
  k_xbar<16><<<2048, 256, 0, stream>>>(x0, es_src, row_start, xbar);
  k_layer<16,48,64,2,8,4,4,16,3,true,96><<<(NN/8)*2, 256, 0, stream>>>(x0, Hbuf, es_src, row_start, c1W2, part);
  k_epi<16,48,8><<<2048, 256, 0, stream>>>(part, x0, xbar, c1rt, c1b2, c1bs, y1);

  // ---- layer 2: IC=48 OC=32 | PLEN=32 KS=4 BN=8 G=2 PP=4 TI=6 | OQ=8 TO=4 | PF on, EB=128 (16 slices)
  k_hmlp<<<2048, 256, 0, stream>>>(es_ea, c2W1, c2b1, Hbuf);
  k_xbar<48><<<2048, 256, 0, stream>>>(y1, es_src, row_start, xbar);
  k_layer<48,32,32,4,8,4,6,8,4,true,128><<<(NN/8)*4, 256, 0, stream>>>(y1, Hbuf, es_src, row_start, c2W2, part);
  k_epi<48,32,16><<<2048, 256, 0, stream>>>(part, y1, xbar, c2rt, c2b2, c2bs, y2);

  // ---- layer 3: IC=32 OC=16 | PLEN=64 KS=2 BN=4 G=1 PP=4 TI=8 | OQ=4 TO=4 | PF on, EB=64 (8 slices)
  k_hmlp<<<2048, 256, 0, stream>>>(es_ea, c3W1, c3b1, Hbuf);
  k_xbar<32><<<2048, 256, 0, stream>>>(y2, es_src, row_start, xbar);
  k_layer<32,16,64,2,4,4,8,4,4,true,64><<<(NN/4)*2, 256, 0, stream>>>(y2, Hbuf, es_src, row_start, c3W2, part);
  k_epi<32,16,8><<<2048, 256, 0, stream>>>(part, y2, xbar, c3rt, c3b2, c3bs, y3);

  // ---- set2set + MLP head
  k_s2s<<<NG, 64, 0, stream>>>(y3, batch, Wih, Whh, bih, bhh, l1W, l1b, l2W, l2b, lfW, lfb, out);
}

// Round 11
// 737.027 us; speedup vs baseline: 1.2985x; 1.0019x over previous
//
#include <hip/hip_runtime.h>

#define NN 20000
#define NE 200000
#define NG 512

typedef float v2f __attribute__((ext_vector_type(2)));

__device__ __forceinline__ int lowerb(const int* a, int n, int v){
  int lo=0, hi=n;
  while(lo<hi){ int m=(lo+hi)>>1; if(a[m]<v) lo=m+1; else hi=m; }
  return lo;
}

// async global->LDS copy, 16B per lane. LDS dest must be linear in lane order
// (wave-uniform base + lane*16). AUX=2 sets NT (evict-first): H stream is single-use.
template<int AUX>
__device__ __forceinline__ void gload_lds16(const float4* g, float4* l){
  __builtin_amdgcn_global_load_lds(
    (const __attribute__((address_space(1))) void*)(g),
    (__attribute__((address_space(3))) void*)(l), 16, 0, AUX);
}

// ---------------- counting sort by tgt -> CSR ----------------
__global__ void k_count(const int* __restrict__ tgt, int* __restrict__ cnt){
  int e = blockIdx.x*blockDim.x + threadIdx.x;
  if(e<NE) atomicAdd(&cnt[tgt[e]], 1);
}

__global__ void k_scan(const int* __restrict__ cnt, int* __restrict__ row_start){
  __shared__ int part[1024];
  int t = threadIdx.x;
  const int CH = (NN + 1023)/1024; // 20
  int i0 = t*CH;
  int s = 0;
  for(int j=0;j<CH;j++){ int i=i0+j; if(i<NN) s += cnt[i]; }
  part[t] = s; __syncthreads();
  for(int d=1; d<1024; d<<=1){
    int v = (t>=d) ? part[t-d] : 0;
    __syncthreads();
    part[t] += v;
    __syncthreads();
  }
  int run = (t==0) ? 0 : part[t-1];
  for(int j=0;j<CH;j++){ int i=i0+j; if(i<NN){ row_start[i]=run; run += cnt[i]; } }
  if(t==0) row_start[NN] = part[1023];
}

// place edges in CSR order AND gather edge_attr to CSR order (fused)
__global__ void k_place(const int* __restrict__ src, const int* __restrict__ tgt,
                        const float* __restrict__ ea,
                        const int* __restrict__ row_start, int* __restrict__ cur,
                        int* __restrict__ es_src, float* __restrict__ es_ea){
  int e = blockIdx.x*blockDim.x + threadIdx.x;
  if(e>=NE) return;
  int n = tgt[e];
  int pos = row_start[n] + atomicAdd(&cur[n],1);
  es_src[pos] = src[e];
  const float4* s = (const float4*)ea + (size_t)e*4;
  float4* d = (float4*)es_ea + (size_t)pos*4;
  d[0]=s[0]; d[1]=s[1]; d[2]=s[2]; d[3]=s[3];
}

// ---------------- H = relu(es_ea @ W1 + b1), CSR-ordered, E x 128 ----------------
// Persistent grid-stride (round-8 aux win) + packed v_pk_fma_f32 math (round 11):
// the FMA inner loop issues half the VALU instructions as v2f pairs.
__launch_bounds__(256, 4)
__global__ void k_hmlp(const float* __restrict__ es_ea, const float* __restrict__ W1,
                       const float* __restrict__ b1, float* __restrict__ H){
  const int pc = threadIdx.x & 31, er = threadIdx.x >> 5;
  v2f w1a[16], w1b[16];
  #pragma unroll
  for(int i=0;i<16;i++){
    float4 w = *(const float4*)&W1[i*128 + pc*4];
    w1a[i] = v2f{w.x, w.y};
    w1b[i] = v2f{w.z, w.w};
  }
  const float4 bv = *(const float4*)&b1[pc*4];
  for(size_t e0 = (size_t)blockIdx.x*8; e0 < NE; e0 += (size_t)gridDim.x*8){
    const size_t e = e0 + er;
    v2f h01 = v2f{bv.x, bv.y}, h23 = v2f{bv.z, bv.w};
    float eav[16];
    const float4* eap = (const float4*)(es_ea + e*16);
    #pragma unroll
    for(int q=0;q<4;q++){
      float4 v = eap[q];
      eav[q*4+0]=v.x; eav[q*4+1]=v.y; eav[q*4+2]=v.z; eav[q*4+3]=v.w;
    }
    #pragma unroll
    for(int i=0;i<16;i++){
      v2f e2 = v2f{eav[i], eav[i]};
      h01 += e2*w1a[i];
      h23 += e2*w1b[i];
    }
    float4 hv;
    hv.x = fmaxf(h01[0],0.f); hv.y = fmaxf(h01[1],0.f);
    hv.z = fmaxf(h23[0],0.f); hv.w = fmaxf(h23[1],0.f);
    *(float4*)&H[e*128 + pc*4] = hv;
  }
}

// ---------------- xbar[n,i] = mean over in-edges of x[src,i] ----------------
// Persistent grid-stride (round-8 aux win).
template<int IC>
__global__ void k_xbar(const float* __restrict__ x, const int* __restrict__ es_src,
                       const int* __restrict__ row_start, float* __restrict__ xbar){
  constexpr int TI = IC/16;
  const int wid = threadIdx.x>>6, lane = threadIdx.x&63;
  const int eg = lane>>4, ig = lane&15;
  for(int n0 = blockIdx.x*4; n0 < NN; n0 += gridDim.x*4){
    const int n = n0 + wid;
    const int a = row_start[n], b = row_start[n+1];
    float s[TI];
    #pragma unroll
    for(int u=0;u<TI;u++) s[u]=0.f;
    for(int e=a+eg; e<b; e+=4){
      int sn = es_src[e];
      #pragma unroll
      for(int u=0;u<TI;u++) s[u] += x[(size_t)sn*IC + ig*TI + u];
    }
    #pragma unroll
    for(int u=0;u<TI;u++){
      s[u] += __shfl_xor(s[u], 16, 64);
      s[u] += __shfl_xor(s[u], 32, 64);
    }
    if(eg==0){
      float dinv = 1.f/fmaxf((float)(b-a), 1.f);
      #pragma unroll
      for(int u=0;u<TI;u++) xbar[(size_t)n*IC + ig*TI + u] = s[u]*dinv;
    }
  }
}

// ---------------- fused NNConv layer: wave-private scatter + coalesced k-split GEMM ----------------
// Round 11: round-10 layer (best measured: L2 237us, VGPR 68) + PACKED fp32 math.
// Diagnosis: L2 at 28% of fp32 peak with 65% VALUBusy -> FMAs are only ~43% of issued
// VALU instructions; issue port is the contended resource. gfx950 has v_pk_fma_f32
// (2 FMA/inst/lane, FeaturePackedFP32Ops); LLVM selects it for <2 x float> fma.
// Scatter packs along TI (4/6/8 all even), GEMM packs along TO (pairs + scalar tail
// for TO=3). Same per-element accumulation order -> identical results.
// All prior lessons intact: PF + W2-only ping-pong (rounds 2/8), S reads in-iteration
// (round 1: dbuf of both spilled), BN=8 for L1/L2 (round 7), no min-waves>3 (rounds
// 4/5), NT on single-use H stream. No-spill check: FETCH ~85-101MB, WRITE 40MB.
template<int IC, int OC, int PLEN, int KS, int BN, int PP, int TI, int OQ, int TO, bool PF, int EB>
__launch_bounds__(256, 3)
__global__ void k_layer(const float* __restrict__ x_in, const float* __restrict__ H,
                        const int* __restrict__ es_src, const int* __restrict__ row_start,
                        const float* __restrict__ W2, float* __restrict__ part)
{
  constexpr int K    = PLEN*IC;
  constexpr int HV4  = PLEN/4;
  constexpr int XV   = IC/4;
  constexpr int NIW  = IC/TI;
  constexpr int NPW  = PLEN/PP;
  constexpr int G    = BN/4;
  constexpr int KQL  = 64/OQ;
  constexpr int TSPL = 4*KQL;
  constexpr int J    = (K/4)/TSPL;
  constexpr int NH4  = (EB*HV4 + 255)/256;   // hb staging chunks
  constexpr int NX4  = (EB*XV  + 255)/256;   // xs staging chunks
  constexpr int TI2  = TI/2;                 // packed pairs along TI
  constexpr int NP   = TO/2;                 // packed pairs along TO
  constexpr bool TODD = (TO & 1);
  static_assert(TI%2==0, "packed scatter needs even TI");
  static_assert(NPW*NIW==64, "wave tile covers 64 lanes");
  static_assert(G*PP*TI <= 48, "spill-safe accumulator");
  static_assert(EB*(PLEN+IC) <= BN*K, "staging alias fits in S");
  static_assert((EB*HV4)%256==0, "hb tail must not round into xs region");
  static_assert(EB*PLEN/4 + NX4*256 <= BN*K/4, "xs tail rounding stays inside S");
  static_assert(OQ*TO==OC && (K/4)%TSPL==0, "gemm tiling");
  static_assert(J%2==0, "ping-pong needs even J");

  __shared__ __align__(16) float S[BN*K];
  __shared__ int rs_s[BN+1], ro[BN+1];

  float* hb = S;                 // EB*PLEN staged H slice
  float* xs = S + EB*PLEN;       // EB*IC staged x[src]

  const int tid = threadIdx.x;
  const int wid = tid>>6, lane = tid&63;
  const int split = blockIdx.x % KS;
  const int nb = blockIdx.x / KS;
  const int n0 = nb*BN;
  const int p04 = split*HV4;

  if(tid<=BN) rs_s[tid] = row_start[n0+tid];
  __syncthreads();
  const int estart = rs_s[0], eend = rs_s[BN];

  const int pw = lane / NIW;
  const int iw = lane - pw*NIW;

  v2f acc2[G][PP][TI2];
  #pragma unroll
  for(int g=0;g<G;g++)
    #pragma unroll
    for(int p=0;p<PP;p++)
      #pragma unroll
      for(int u=0;u<TI2;u++) acc2[g][p][u]=v2f{0.f,0.f};

  const float4* H4 = (const float4*)H;
  const float4* x4 = (const float4*)x_in;

  for(int bstart=estart; bstart<eend; bstart+=EB){
    const int ebc = min(EB, eend-bstart);
    if(tid<=BN){ int v = rs_s[tid]-bstart; ro[tid] = min(max(v,0), ebc); }
    const int hb_lim = ebc*HV4, xs_lim = ebc*XV;
    // pre-load gather indices (independent loads, issued together)
    int sn_r[NX4];
    #pragma unroll
    for(int c=0;c<NX4;c++){
      int jc = min(tid + c*256, xs_lim-1);
      sn_r[c] = es_src[bstart + jc/XV];
    }
    // async H slice -> hb (NT: single-use stream)
    #pragma unroll
    for(int c=0;c<NH4;c++){
      int j = tid + c*256;
      int jc = min(j, hb_lim-1);
      int e = jc/HV4, q = jc - e*HV4;
      gload_lds16<2>(H4 + (size_t)(bstart+e)*32 + p04 + q, ((float4*)hb) + j);
    }
    // async x[src] -> xs (temporal: reused across blocks)
    #pragma unroll
    for(int c=0;c<NX4;c++){
      int j = tid + c*256;
      int jc = min(j, xs_lim-1);
      int q = jc - (jc/XV)*XV;
      gload_lds16<0>(x4 + (size_t)sn_r[c]*XV + q, ((float4*)xs) + j);
    }
    __syncthreads();   // drains vmcnt (global_load_lds tracked there)
    // wave-private scatter (only the owning wave touches its nodes' edges)
    if constexpr (PF){
      #pragma unroll
      for(int g=0; g<G; g++){
        const int nl = wid*G + g;
        const int a = ro[nl], b = ro[nl+1];
        if(a>=b) continue;
        float hv[PP]; v2f xv2[TI2];
        #pragma unroll
        for(int p=0;p<PP;p++) hv[p] = hb[a*PLEN + pw*PP + p];
        #pragma unroll
        for(int u=0;u<TI2;u++) xv2[u] = *(const v2f*)&xs[a*IC + iw*TI + 2*u];
        for(int e=a; e<b; e++){
          float hn[PP]; v2f xn2[TI2];
          if(e+1<b){
            #pragma unroll
            for(int p=0;p<PP;p++) hn[p] = hb[(e+1)*PLEN + pw*PP + p];
            #pragma unroll
            for(int u=0;u<TI2;u++) xn2[u] = *(const v2f*)&xs[(e+1)*IC + iw*TI + 2*u];
          }
          #pragma unroll
          for(int p=0;p<PP;p++){
            v2f h2 = v2f{hv[p], hv[p]};
            #pragma unroll
            for(int u=0;u<TI2;u++) acc2[g][p][u] += h2*xv2[u];
          }
          #pragma unroll
          for(int p=0;p<PP;p++) hv[p]=hn[p];
          #pragma unroll
          for(int u=0;u<TI2;u++) xv2[u]=xn2[u];
        }
      }
    } else {
      #pragma unroll
      for(int g=0; g<G; g++){
        const int nl = wid*G + g;
        const int a = ro[nl], b = ro[nl+1];
        for(int e=a; e<b; e++){
          float hv[PP];
          #pragma unroll
          for(int p=0;p<PP;p++) hv[p] = hb[e*PLEN + pw*PP + p];
          v2f xv2[TI2];
          #pragma unroll
          for(int u=0;u<TI2;u++) xv2[u] = *(const v2f*)&xs[e*IC + iw*TI + 2*u];
          #pragma unroll
          for(int p=0;p<PP;p++){
            v2f h2 = v2f{hv[p], hv[p]};
            #pragma unroll
            for(int u=0;u<TI2;u++) acc2[g][p][u] += h2*xv2[u];
          }
        }
      }
    }
    __syncthreads();
  }

  // dump scaled S (staging area dead)
  #pragma unroll
  for(int g=0; g<G; g++){
    const int nl = wid*G + g;
    const float dv = 1.f/fmaxf((float)(rs_s[nl+1]-rs_s[nl]), 1.f);
    const v2f dv2 = v2f{dv, dv};
    #pragma unroll
    for(int p=0;p<PP;p++)
      #pragma unroll
      for(int u=0;u<TI2;u++)
        *(v2f*)&S[(nl*PLEN + pw*PP + p)*IC + iw*TI + 2*u] = acc2[g][p][u]*dv2;
  }

  // ---- GEMM: slice[n][o] partial over this wave's k-range; coalesced W2 ----
  const int oq  = lane % OQ;
  const int kql = lane / OQ;
  const int o0  = oq*TO;
  const float* W2b = W2 + (size_t)split*K*OC + o0;

  auto LOADW = [&](int j, v2f (&wv2)[4][NP], float (&wvs)[4]){
    const int k4 = j*TSPL + wid*KQL + kql;
    #pragma unroll
    for(int r=0;r<4;r++){
      const float* wr = W2b + (size_t)(4*k4+r)*OC;
      if constexpr (TO==4){
        float4 a=*(const float4*)wr;
        wv2[r][0]=v2f{a.x,a.y}; wv2[r][1]=v2f{a.z,a.w};
      } else if constexpr (TO==3){
        wv2[r][0]=v2f{wr[0],wr[1]}; wvs[r]=wr[2];
      } else {
        float2 a=*(const float2*)wr;
        wv2[r][0]=v2f{a.x,a.y};
      }
    }
  };

  v2f outp2[BN][NP];
  float outs[BN];
  #pragma unroll
  for(int n=0;n<BN;n++){
    #pragma unroll
    for(int t=0;t<NP;t++) outp2[n][t]=v2f{0.f,0.f};
    outs[n]=0.f;
  }

  v2f wvA[4][NP], wvB[4][NP];
  float wsA[4], wsB[4];
  LOADW(0, wvA, wsA);     // W2 j=0 in flight across the barrier (independent of S)
  __syncthreads();        // S visible to all waves

  #pragma unroll 1
  for(int j=0;j<J;j+=2){
    LOADW(j+1, wvB, wsB); // prefetch while FMAs on wvA run
    {
      const int k4 = j*TSPL + wid*KQL + kql;
      #pragma unroll
      for(int n=0;n<BN;n++){
        float4 sv = *(const float4*)&S[n*K + 4*k4];
        v2f s0=v2f{sv.x,sv.x}, s1=v2f{sv.y,sv.y}, s2=v2f{sv.z,sv.z}, s3=v2f{sv.w,sv.w};
        #pragma unroll
        for(int t=0;t<NP;t++)
          outp2[n][t] += s0*wvA[0][t] + s1*wvA[1][t] + s2*wvA[2][t] + s3*wvA[3][t];
        if constexpr (TODD)
          outs[n] += sv.x*wsA[0] + sv.y*wsA[1] + sv.z*wsA[2] + sv.w*wsA[3];
      }
    }
    if(j+2<J) LOADW(j+2, wvA, wsA);   // prefetch while FMAs on wvB run
    {
      const int k4 = (j+1)*TSPL + wid*KQL + kql;
      #pragma unroll
      for(int n=0;n<BN;n++){
        float4 sv = *(const float4*)&S[n*K + 4*k4];
        v2f s0=v2f{sv.x,sv.x}, s1=v2f{sv.y,sv.y}, s2=v2f{sv.z,sv.z}, s3=v2f{sv.w,sv.w};
        #pragma unroll
        for(int t=0;t<NP;t++)
          outp2[n][t] += s0*wvB[0][t] + s1*wvB[1][t] + s2*wvB[2][t] + s3*wvB[3][t];
        if constexpr (TODD)
          outs[n] += sv.x*wsB[0] + sv.y*wsB[1] + sv.z*wsB[2] + sv.w*wsB[3];
      }
    }
  }

  // intra-wave reduce over kql lanes (masks OQ..32)
  #pragma unroll
  for(int m=OQ; m<64; m<<=1)
    #pragma unroll
    for(int n=0;n<BN;n++){
      #pragma unroll
      for(int t=0;t<NP;t++){
        outp2[n][t][0] += __shfl_xor(outp2[n][t][0], m, 64);
        outp2[n][t][1] += __shfl_xor(outp2[n][t][1], m, 64);
      }
      if constexpr (TODD) outs[n] += __shfl_xor(outs[n], m, 64);
    }

  if(kql==0){
    float* slice = part + (size_t)(split*4+wid)*NN*OC;
    #pragma unroll
    for(int n=0;n<BN;n++){
      float* dst = slice + (size_t)(n0+n)*OC + o0;
      if constexpr (TO==4){
        *(float4*)dst = make_float4(outp2[n][0][0],outp2[n][0][1],outp2[n][1][0],outp2[n][1][1]);
      } else if constexpr (TO==3){
        dst[0]=outp2[n][0][0]; dst[1]=outp2[n][0][1]; dst[2]=outs[n];
      } else {
        *(float2*)dst = make_float2(outp2[n][0][0],outp2[n][0][1]);
      }
    }
  }
}

// ---------------- epilogue: y = relu(sum_s part[s] + x@root + xbar@b2 + bias) ----------------
// Grid-stride (round-8 aux win).
template<int IC, int OC, int SL>
__global__ void k_epi(const float* __restrict__ part, const float* __restrict__ x,
                      const float* __restrict__ xbar,
                      const float* __restrict__ root, const float* __restrict__ b2,
                      const float* __restrict__ bias, float* __restrict__ y)
{
  for(int idx = blockIdx.x*256 + threadIdx.x; idx < NN*OC; idx += gridDim.x*256){
    int n = idx/OC, o = idx - n*OC;
    float v = bias[o];
    #pragma unroll
    for(int s=0;s<SL;s++) v += part[(size_t)s*NN*OC + idx];
    #pragma unroll
    for(int i=0;i<IC;i++) v += x[(size_t)n*IC+i]*root[i*OC+o];
    #pragma unroll
    for(int i=0;i<IC;i++) v += xbar[(size_t)n*IC+i]*b2[i*OC+o];
    y[idx] = fmaxf(v, 0.f);
  }
}

// ---------------- set2set (2 steps) + final MLP, one wave per graph ----------------
__global__ void k_s2s(const float* __restrict__ xg, const int* __restrict__ batch,
  const float* __restrict__ Wih, const float* __restrict__ Whh,
  const float* __restrict__ bih, const float* __restrict__ bhh,
  const float* __restrict__ l1W, const float* __restrict__ l1b,
  const float* __restrict__ l2W, const float* __restrict__ l2b,
  const float* __restrict__ lfW, const float* __restrict__ lfb,
  float* __restrict__ out)
{
  int g = blockIdx.x, lane = threadIdx.x;
  __shared__ float hs[16], cs[16], qs[32], gs[64], rs[16];
  int r0 = lowerb(batch, NN, g);
  int r1 = lowerb(batch, NN, g+1);
  if(lane<16){ hs[lane]=0.f; cs[lane]=0.f; }
  if(lane<32) qs[lane]=0.f;
  __syncthreads();
  for(int step=0; step<2; step++){
    float gate = bih[lane] + bhh[lane];
    for(int k=0;k<32;k++) gate += qs[k]*Wih[lane*32+k];
    for(int k=0;k<16;k++) gate += hs[k]*Whh[lane*16+k];
    gs[lane] = gate;
    __syncthreads();
    if(lane<16){
      float ig = 1.f/(1.f+expf(-gs[lane]));
      float fg = 1.f/(1.f+expf(-gs[lane+16]));
      float gg = tanhf(gs[lane+32]);
      float og = 1.f/(1.f+expf(-gs[lane+48]));
      float cn = fg*cs[lane] + ig*gg;
      cs[lane] = cn;
      hs[lane] = og*tanhf(cn);
    }
    __syncthreads();
    float m = -1e30f;
    for(int n=r0+lane; n<r1; n+=64){
      float e=0.f;
      for(int k=0;k<16;k++) e += xg[n*16+k]*hs[k];
      m = fmaxf(m, e);
    }
    for(int d=1; d<64; d<<=1) m = fmaxf(m, __shfl_xor(m, d));
    float ssum = 0.f;
    float racc[16];
    #pragma unroll
    for(int k=0;k<16;k++) racc[k]=0.f;
    for(int n=r0+lane; n<r1; n+=64){
      float e=0.f, xv[16];
      #pragma unroll
      for(int k=0;k<16;k++){ xv[k]=xg[n*16+k]; e += xv[k]*hs[k]; }
      float a = expf(e - m);
      ssum += a;
      #pragma unroll
      for(int k=0;k<16;k++) racc[k] += a*xv[k];
    }
    for(int d=1; d<64; d<<=1) ssum += __shfl_xor(ssum, d);
    #pragma unroll
    for(int k=0;k<16;k++)
      for(int d=1; d<64; d<<=1) racc[k] += __shfl_xor(racc[k], d);
    ssum = fmaxf(ssum, 1e-16f);
    if(lane==0){
      #pragma unroll
      for(int k=0;k<16;k++) rs[k] = racc[k]/ssum;
    }
    __syncthreads();
    if(lane<16){ qs[lane]=hs[lane]; qs[16+lane]=rs[lane]; }
    __syncthreads();
  }
  if(lane<16){
    float v = l1b[lane];
    for(int k=0;k<32;k++) v += qs[k]*l1W[k*16+lane];
    gs[lane] = fmaxf(v,0.f);
  }
  __syncthreads();
  if(lane<8){
    float v = l2b[lane];
    for(int k=0;k<16;k++) v += gs[k]*l2W[k*8+lane];
    gs[32+lane] = fmaxf(v,0.f);
  }
  __syncthreads();
  if(lane==0){
    float v = lfb[0];
    for(int k=0;k<8;k++) v += gs[32+k]*lfW[k];
    out[g] = v;
  }
}

extern "C" void kernel_launch(void* const* d_in, const int* in_sizes, int n_in,
                              void* d_out, int out_size, void* d_ws, size_t ws_size,
                              hipStream_t stream) {
  const float* x0   = (const float*)d_in[0];
  const int*   ei   = (const int*)d_in[1];
  const float* ea   = (const float*)d_in[2];
  const int*   batch= (const int*)d_in[3];
  const float* c1W1 = (const float*)d_in[4];  const float* c1b1 = (const float*)d_in[5];
  const float* c1W2 = (const float*)d_in[6];  const float* c1b2 = (const float*)d_in[7];
  const float* c1rt = (const float*)d_in[8];  const float* c1bs = (const float*)d_in[9];
  const float* c2W1 = (const float*)d_in[10]; const float* c2b1 = (const float*)d_in[11];
  const float* c2W2 = (const float*)d_in[12]; const float* c2b2 = (const float*)d_in[13];
  const float* c2rt = (const float*)d_in[14]; const float* c2bs = (const float*)d_in[15];
  const float* c3W1 = (const float*)d_in[16]; const float* c3b1 = (const float*)d_in[17];
  const float* c3W2 = (const float*)d_in[18]; const float* c3b2 = (const float*)d_in[19];
  const float* c3rt = (const float*)d_in[20]; const float* c3bs = (const float*)d_in[21];
  const float* Wih  = (const float*)d_in[22]; const float* Whh  = (const float*)d_in[23];
  const float* bih  = (const float*)d_in[24]; const float* bhh  = (const float*)d_in[25];
  const float* l1W  = (const float*)d_in[26]; const float* l1b  = (const float*)d_in[27];
  const float* l2W  = (const float*)d_in[28]; const float* l2b  = (const float*)d_in[29];
  const float* lfW  = (const float*)d_in[30]; const float* lfb  = (const float*)d_in[31];
  float* out = (float*)d_out;

  const int* src = ei;
  const int* tgt = ei + NE;

  // workspace carve (~190 MB)
  char* w = (char*)d_ws;
  auto carve = [&](size_t bytes)->void*{ void* p = (void*)w; w += (bytes + 255) & ~(size_t)255; return p; };
  int*   row_start = (int*)carve((NN+1)*sizeof(int));
  int*   cur       = (int*)carve(NN*sizeof(int));
  int*   es_src    = (int*)carve(NE*sizeof(int));
  float* es_ea     = (float*)carve((size_t)NE*16*sizeof(float));
  float* Hbuf      = (float*)carve((size_t)NE*128*sizeof(float));
  float* xbar      = (float*)carve((size_t)NN*48*sizeof(float));
  float* y1   = (float*)carve((size_t)NN*48*sizeof(float));
  float* y2   = (float*)carve((size_t)NN*32*sizeof(float));
  float* y3   = (float*)carve((size_t)NN*16*sizeof(float));
  float* part = (float*)carve((size_t)16*NN*48*sizeof(float)); // up to 16 slices

  // ---- CSR by tgt (+ fused ea gather)
  hipMemsetAsync(cur, 0, NN*sizeof(int), stream);
  k_count<<<(NE+255)/256, 256, 0, stream>>>(tgt, cur);
  k_scan<<<1, 1024, 0, stream>>>(cur, row_start);
  hipMemsetAsync(cur, 0, NN*sizeof(int), stream);
  k_place<<<(NE+255)/256, 256, 0, stream>>>(src, tgt, ea, row_start, cur, es_src, es_ea);

  // ---- layer 1: IC=16 OC=48 | PLEN=64 KS=2 BN=8 G=2 PP=4 TI=4 | OQ=16 TO=3 | PF on, EB=96 (8 slices)
  k_hmlp<<<2048, 256, 0, stream>>>(es_ea, c1W1, c1b1, Hbuf);
  k_xbar<16><<<2048, 256, 0, stream>>>(x0, es_src, row_start, xbar);
  k_layer<16,48,64,2,8,4,4,16,3,true,96><<<(NN/8)*2, 256, 0, stream>>>(x0, Hbuf, es_src, row_start, c1W2, part);
  k_epi<16,48,8><<<2048, 256, 0, stream>>>(part, x0, xbar, c1rt, c1b2, c1bs, y1);

  // ---- layer 2: IC=48 OC=32 | PLEN=32 KS=4 BN=8 G=2 PP=4 TI=6 | OQ=8 TO=4 | PF on, EB=128 (16 slices)
  k_hmlp<<<2048, 256, 0, stream>>>(es_ea, c2W1, c2b1, Hbuf);
  k_xbar<48><<<2048, 256, 0, stream>>>(y1, es_src, row_start, xbar);
  k_layer<48,32,32,4,8,4,6,8,4,true,128><<<(NN/8)*4, 256, 0, stream>>>(y1, Hbuf, es_src, row_start, c2W2, part);
  k_epi<48,32,16><<<2048, 256, 0, stream>>>(part, y1, xbar, c2rt, c2b2, c2bs, y2);

  // ---- layer 3: IC=32 OC=16 | PLEN=64 KS=2 BN=4 G=1 PP=4 TI=8 | OQ=4 TO=4 | PF on, EB=64 (8 slices)
  k_hmlp<<<2048, 256, 0, stream>>>(es_ea, c3W1, c3b1, Hbuf);
  k_xbar<32><<<2048, 256, 0, stream>>>(y2, es_src, row_start, xbar);
  k_layer<32,16,64,2,4,4,8,4,4,true,64><<<(NN/4)*2, 256, 0, stream>>>(y2, Hbuf, es_src, row_start, c3W2, part);
  k_epi<32,16,8><<<2048, 256, 0, stream>>>(part, y2, xbar, c3rt, c3b2, c3bs, y3);

  // ---- set2set + MLP head
  k_s2s<<<NG, 64, 0, stream>>>(y3, batch, Wih, Whh, bih, bhh, l1W, l1b, l2W, l2b, lfW, lfb, out);
}

// Round 12
// 723.472 us; speedup vs baseline: 1.3229x; 1.0187x over previous
//
#include <hip/hip_runtime.h>

#define NN 20000
#define NE 200000
#define NG 512

typedef float v2f __attribute__((ext_vector_type(2)));

__device__ __forceinline__ int lowerb(const int* a, int n, int v){
  int lo=0, hi=n;
  while(lo<hi){ int m=(lo+hi)>>1; if(a[m]<v) lo=m+1; else hi=m; }
  return lo;
}

// async global->LDS copy, 16B per lane. LDS dest must be linear in lane order
// (wave-uniform base + lane*16).
template<int AUX>
__device__ __forceinline__ void gload_lds16(const float4* g, float4* l){
  __builtin_amdgcn_global_load_lds(
    (const __attribute__((address_space(1))) void*)(g),
    (__attribute__((address_space(3))) void*)(l), 16, 0, AUX);
}

// ---------------- counting sort by tgt -> CSR ----------------
__global__ void k_count(const int* __restrict__ tgt, int* __restrict__ cnt){
  int e = blockIdx.x*blockDim.x + threadIdx.x;
  if(e<NE) atomicAdd(&cnt[tgt[e]], 1);
}

__global__ void k_scan(const int* __restrict__ cnt, int* __restrict__ row_start){
  __shared__ int part[1024];
  int t = threadIdx.x;
  const int CH = (NN + 1023)/1024; // 20
  int i0 = t*CH;
  int s = 0;
  for(int j=0;j<CH;j++){ int i=i0+j; if(i<NN) s += cnt[i]; }
  part[t] = s; __syncthreads();
  for(int d=1; d<1024; d<<=1){
    int v = (t>=d) ? part[t-d] : 0;
    __syncthreads();
    part[t] += v;
    __syncthreads();
  }
  int run = (t==0) ? 0 : part[t-1];
  for(int j=0;j<CH;j++){ int i=i0+j; if(i<NN){ row_start[i]=run; run += cnt[i]; } }
  if(t==0) row_start[NN] = part[1023];
}

// place edges in CSR order AND gather edge_attr to CSR order (fused)
__global__ void k_place(const int* __restrict__ src, const int* __restrict__ tgt,
                        const float* __restrict__ ea,
                        const int* __restrict__ row_start, int* __restrict__ cur,
                        int* __restrict__ es_src, float* __restrict__ es_ea){
  int e = blockIdx.x*blockDim.x + threadIdx.x;
  if(e>=NE) return;
  int n = tgt[e];
  int pos = row_start[n] + atomicAdd(&cur[n],1);
  es_src[pos] = src[e];
  const float4* s = (const float4*)ea + (size_t)e*4;
  float4* d = (float4*)es_ea + (size_t)pos*4;
  d[0]=s[0]; d[1]=s[1]; d[2]=s[2]; d[3]=s[3];
}

// ---------------- fused NNConv layer ----------------
// Round 12: FUSE edge-MLP (was k_hmlp) and xbar (was k_xbar) into the layer.
//  - H fusion: splits partition H's columns, so each split computes only its
//    PLEN-slice of relu(ea@W1+b1) in the staging phase -> ZERO recompute, kills
//    the 102MB/layer H write + re-read and 3 dispatches. Per-thread W1 column
//    (16 regs) hoisted; ea staged to LDS (CSR-linear -> gload_lds-friendly).
//  - xbar fusion: every split already stages x[src] per edge; split-0 waves
//    accumulate xsum per edge (TI2 pk-adds) and write xbar. Kills 3 dispatches.
//  - LDS: [hb EB*PLEN][ea EB*16][xs EB*IC], each region an exact multiple of
//    256 float4 (asserted) so clamped-tail async writes never cross regions
//    (two in-flight gload_lds to one address = race). L1 EB 96->64 to fit.
//  - VGPR ~95-115 expected: FREE here -- LDS 48.5KB binds occupancy at 3 blocks
//    = 12 waves/CU for any VGPR<=128 (round-9's 84-VGPR failure was only fatal
//    with 25KB LDS where 24 waves were eligible). Cap 128 is the revert line.
// All prior lessons intact: PF scatter prefetch + W2-only ping-pong (rounds 2/8),
// S reads in-iteration (round 1), BN=8 for L1/L2 (round 7), no min-waves>3
// (rounds 4/5). No-spill check: WRITE ~44MB, VGPR<=128, FETCH ~50-70MB.
template<int IC, int OC, int PLEN, int KS, int BN, int PP, int TI, int OQ, int TO, bool PF, int EB>
__launch_bounds__(256, 3)
__global__ void k_layer(const float* __restrict__ x_in, const float* __restrict__ es_ea,
                        const int* __restrict__ es_src, const int* __restrict__ row_start,
                        const float* __restrict__ W1, const float* __restrict__ b1,
                        const float* __restrict__ W2, float* __restrict__ part,
                        float* __restrict__ xbar_out)
{
  constexpr int K    = PLEN*IC;
  constexpr int XV   = IC/4;
  constexpr int NIW  = IC/TI;
  constexpr int NPW  = PLEN/PP;
  constexpr int G    = BN/4;
  constexpr int KQL  = 64/OQ;
  constexpr int TSPL = 4*KQL;
  constexpr int J    = (K/4)/TSPL;
  constexpr int NEA  = EB/64;            // ea staging chunks (EB*16/4/256)
  constexpr int NX4  = (EB*XV)/256;      // xs staging chunks (exact)
  constexpr int TI2  = TI/2;
  constexpr int NP   = TO/2;
  constexpr bool TODD = (TO & 1);
  constexpr int EPB  = 256/PLEN;         // edges per H-compute iteration
  static_assert(TI%2==0, "packed scatter needs even TI");
  static_assert(256%PLEN==0, "H-compute mapping");
  static_assert(EB%64==0, "ea region must be exact 256-f4 chunks");
  static_assert((EB*XV)%256==0, "xs region must be exact 256-f4 chunks");
  static_assert(EB*(PLEN+16+IC) <= BN*K, "staging alias fits in S");
  static_assert(NPW*NIW==64, "wave tile covers 64 lanes");
  static_assert(G*PP*TI <= 48, "spill-safe accumulator");
  static_assert(OQ*TO==OC && (K/4)%TSPL==0, "gemm tiling");
  static_assert(J%2==0, "ping-pong needs even J");

  __shared__ __align__(16) float S[BN*K];
  __shared__ int rs_s[BN+1], ro[BN+1];

  float* hb  = S;                        // EB*PLEN computed H slice
  float* eas = S + EB*PLEN;              // EB*16 staged edge_attr
  float* xs  = S + EB*(PLEN+16);         // EB*IC staged x[src]

  const int tid = threadIdx.x;
  const int wid = tid>>6, lane = tid&63;
  const int split = blockIdx.x % KS;
  const int nb = blockIdx.x / KS;
  const int n0 = nb*BN;

  if(tid<=BN) rs_s[tid] = row_start[n0+tid];
  __syncthreads();
  const int estart = rs_s[0], eend = rs_s[BN];

  const int pw = lane / NIW;
  const int iw = lane - pw*NIW;
  const int pcol = tid % PLEN, erow = tid / PLEN;

  // per-split W1 column + bias (hoisted; coalesced loads)
  float w1c[16];
  const float b1c = b1[split*PLEN + pcol];
  #pragma unroll
  for(int i=0;i<16;i++) w1c[i] = W1[i*128 + split*PLEN + pcol];

  v2f acc2[G][PP][TI2];
  v2f xsum2[G][TI2];
  #pragma unroll
  for(int g=0;g<G;g++){
    #pragma unroll
    for(int p=0;p<PP;p++)
      #pragma unroll
      for(int u=0;u<TI2;u++) acc2[g][p][u]=v2f{0.f,0.f};
    #pragma unroll
    for(int u=0;u<TI2;u++) xsum2[g][u]=v2f{0.f,0.f};
  }

  const float4* EA4 = (const float4*)es_ea;
  const float4* x4  = (const float4*)x_in;

  for(int bstart=estart; bstart<eend; bstart+=EB){
    const int ebc = min(EB, eend-bstart);
    if(tid<=BN){ int v = rs_s[tid]-bstart; ro[tid] = min(max(v,0), ebc); }
    const int ea_lim = ebc*4, xs_lim = ebc*XV;
    // pre-load gather indices (independent loads, issued together)
    int sn_r[NX4];
    #pragma unroll
    for(int c=0;c<NX4;c++){
      int jc = min(tid + c*256, xs_lim-1);
      sn_r[c] = es_src[bstart + jc/XV];
    }
    // async edge_attr -> eas (CSR-linear source)
    #pragma unroll
    for(int c=0;c<NEA;c++){
      int j = tid + c*256;
      int jc = min(j, ea_lim-1);
      gload_lds16<0>(EA4 + (size_t)bstart*4 + jc, ((float4*)eas) + j);
    }
    // async x[src] -> xs
    #pragma unroll
    for(int c=0;c<NX4;c++){
      int j = tid + c*256;
      int jc = min(j, xs_lim-1);
      int q = jc - (jc/XV)*XV;
      gload_lds16<0>(x4 + (size_t)sn_r[c]*XV + q, ((float4*)xs) + j);
    }
    __syncthreads();   // drains vmcnt (global_load_lds tracked there)

    // ---- compute H slice into hb: h[e][p] = relu(ea_e . W1col_p + b1_p) ----
    for(int ec = erow; ec < ebc; ec += EPB){
      float h = b1c;
      #pragma unroll
      for(int q=0;q<4;q++){
        float4 a = *(const float4*)&eas[ec*16 + 4*q];   // broadcast within group
        h += a.x*w1c[4*q] + a.y*w1c[4*q+1] + a.z*w1c[4*q+2] + a.w*w1c[4*q+3];
      }
      hb[ec*PLEN + pcol] = fmaxf(h, 0.f);
    }
    __syncthreads();

    // ---- wave-private scatter (only the owning wave touches its nodes' edges) ----
    if constexpr (PF){
      #pragma unroll
      for(int g=0; g<G; g++){
        const int nl = wid*G + g;
        const int a = ro[nl], b = ro[nl+1];
        if(a>=b) continue;
        float hv[PP]; v2f xv2[TI2];
        #pragma unroll
        for(int p=0;p<PP;p++) hv[p] = hb[a*PLEN + pw*PP + p];
        #pragma unroll
        for(int u=0;u<TI2;u++) xv2[u] = *(const v2f*)&xs[a*IC + iw*TI + 2*u];
        for(int e=a; e<b; e++){
          float hn[PP]; v2f xn2[TI2];
          if(e+1<b){
            #pragma unroll
            for(int p=0;p<PP;p++) hn[p] = hb[(e+1)*PLEN + pw*PP + p];
            #pragma unroll
            for(int u=0;u<TI2;u++) xn2[u] = *(const v2f*)&xs[(e+1)*IC + iw*TI + 2*u];
          }
          #pragma unroll
          for(int p=0;p<PP;p++){
            v2f h2 = v2f{hv[p], hv[p]};
            #pragma unroll
            for(int u=0;u<TI2;u++) acc2[g][p][u] += h2*xv2[u];
          }
          #pragma unroll
          for(int u=0;u<TI2;u++) xsum2[g][u] += xv2[u];
          #pragma unroll
          for(int p=0;p<PP;p++) hv[p]=hn[p];
          #pragma unroll
          for(int u=0;u<TI2;u++) xv2[u]=xn2[u];
        }
      }
    } else {
      #pragma unroll
      for(int g=0; g<G; g++){
        const int nl = wid*G + g;
        const int a = ro[nl], b = ro[nl+1];
        for(int e=a; e<b; e++){
          float hv[PP];
          #pragma unroll
          for(int p=0;p<PP;p++) hv[p] = hb[e*PLEN + pw*PP + p];
          v2f xv2[TI2];
          #pragma unroll
          for(int u=0;u<TI2;u++) xv2[u] = *(const v2f*)&xs[e*IC + iw*TI + 2*u];
          #pragma unroll
          for(int p=0;p<PP;p++){
            v2f h2 = v2f{hv[p], hv[p]};
            #pragma unroll
            for(int u=0;u<TI2;u++) acc2[g][p][u] += h2*xv2[u];
          }
          #pragma unroll
          for(int u=0;u<TI2;u++) xsum2[g][u] += xv2[u];
        }
      }
    }
    __syncthreads();
  }

  // xbar write (split 0 only; pw==0 lanes hold the full iw-slice sums)
  if(split==0 && pw==0){
    #pragma unroll
    for(int g=0;g<G;g++){
      const int nl = wid*G + g;
      const float dv = 1.f/fmaxf((float)(rs_s[nl+1]-rs_s[nl]), 1.f);
      #pragma unroll
      for(int u=0;u<TI2;u++){
        v2f r = xsum2[g][u]*v2f{dv,dv};
        *(v2f*)&xbar_out[(size_t)(n0+nl)*IC + iw*TI + 2*u] = r;
      }
    }
  }

  // dump scaled S (staging area dead)
  #pragma unroll
  for(int g=0; g<G; g++){
    const int nl = wid*G + g;
    const float dv = 1.f/fmaxf((float)(rs_s[nl+1]-rs_s[nl]), 1.f);
    const v2f dv2 = v2f{dv, dv};
    #pragma unroll
    for(int p=0;p<PP;p++)
      #pragma unroll
      for(int u=0;u<TI2;u++)
        *(v2f*)&S[(nl*PLEN + pw*PP + p)*IC + iw*TI + 2*u] = acc2[g][p][u]*dv2;
  }

  // ---- GEMM: slice[n][o] partial over this wave's k-range; coalesced W2 ----
  const int oq  = lane % OQ;
  const int kql = lane / OQ;
  const int o0  = oq*TO;
  const float* W2b = W2 + (size_t)split*K*OC + o0;

  auto LOADW = [&](int j, v2f (&wv2)[4][NP], float (&wvs)[4]){
    const int k4 = j*TSPL + wid*KQL + kql;
    #pragma unroll
    for(int r=0;r<4;r++){
      const float* wr = W2b + (size_t)(4*k4+r)*OC;
      if constexpr (TO==4){
        float4 a=*(const float4*)wr;
        wv2[r][0]=v2f{a.x,a.y}; wv2[r][1]=v2f{a.z,a.w};
      } else if constexpr (TO==3){
        wv2[r][0]=v2f{wr[0],wr[1]}; wvs[r]=wr[2];
      } else {
        float2 a=*(const float2*)wr;
        wv2[r][0]=v2f{a.x,a.y};
      }
    }
  };

  v2f outp2[BN][NP];
  float outs[BN];
  #pragma unroll
  for(int n=0;n<BN;n++){
    #pragma unroll
    for(int t=0;t<NP;t++) outp2[n][t]=v2f{0.f,0.f};
    outs[n]=0.f;
  }

  v2f wvA[4][NP], wvB[4][NP];
  float wsA[4], wsB[4];
  LOADW(0, wvA, wsA);     // W2 j=0 in flight across the barrier (independent of S)
  __syncthreads();        // S visible to all waves

  #pragma unroll 1
  for(int j=0;j<J;j+=2){
    LOADW(j+1, wvB, wsB); // prefetch while FMAs on wvA run
    {
      const int k4 = j*TSPL + wid*KQL + kql;
      #pragma unroll
      for(int n=0;n<BN;n++){
        float4 sv = *(const float4*)&S[n*K + 4*k4];
        v2f s0=v2f{sv.x,sv.x}, s1=v2f{sv.y,sv.y}, s2=v2f{sv.z,sv.z}, s3=v2f{sv.w,sv.w};
        #pragma unroll
        for(int t=0;t<NP;t++)
          outp2[n][t] += s0*wvA[0][t] + s1*wvA[1][t] + s2*wvA[2][t] + s3*wvA[3][t];
        if constexpr (TODD)
          outs[n] += sv.x*wsA[0] + sv.y*wsA[1] + sv.z*wsA[2] + sv.w*wsA[3];
      }
    }
    if(j+2<J) LOADW(j+2, wvA, wsA);   // prefetch while FMAs on wvB run
    {
      const int k4 = (j+1)*TSPL + wid*KQL + kql;
      #pragma unroll
      for(int n=0;n<BN;n++){
        float4 sv = *(const float4*)&S[n*K + 4*k4];
        v2f s0=v2f{sv.x,sv.x}, s1=v2f{sv.y,sv.y}, s2=v2f{sv.z,sv.z}, s3=v2f{sv.w,sv.w};
        #pragma unroll
        for(int t=0;t<NP;t++)
          outp2[n][t] += s0*wvB[0][t] + s1*wvB[1][t] + s2*wvB[2][t] + s3*wvB[3][t];
        if constexpr (TODD)
          outs[n] += sv.x*wsB[0] + sv.y*wsB[1] + sv.z*wsB[2] + sv.w*wsB[3];
      }
    }
  }

  // intra-wave reduce over kql lanes (masks OQ..32)
  #pragma unroll
  for(int m=OQ; m<64; m<<=1)
    #pragma unroll
    for(int n=0;n<BN;n++){
      #pragma unroll
      for(int t=0;t<NP;t++){
        outp2[n][t][0] += __shfl_xor(outp2[n][t][0], m, 64);
        outp2[n][t][1] += __shfl_xor(outp2[n][t][1], m, 64);
      }
      if constexpr (TODD) outs[n] += __shfl_xor(outs[n], m, 64);
    }

  if(kql==0){
    float* slice = part + (size_t)(split*4+wid)*NN*OC;
    #pragma unroll
    for(int n=0;n<BN;n++){
      float* dst = slice + (size_t)(n0+n)*OC + o0;
      if constexpr (TO==4){
        *(float4*)dst = make_float4(outp2[n][0][0],outp2[n][0][1],outp2[n][1][0],outp2[n][1][1]);
      } else if constexpr (TO==3){
        dst[0]=outp2[n][0][0]; dst[1]=outp2[n][0][1]; dst[2]=outs[n];
      } else {
        *(float2*)dst = make_float2(outp2[n][0][0],outp2[n][0][1]);
      }
    }
  }
}

// ---------------- epilogue: y = relu(sum_s part[s] + x@root + xbar@b2 + bias) ----------------
// Grid-stride (round-8 aux win).
template<int IC, int OC, int SL>
__global__ void k_epi(const float* __restrict__ part, const float* __restrict__ x,
                      const float* __restrict__ xbar,
                      const float* __restrict__ root, const float* __restrict__ b2,
                      const float* __restrict__ bias, float* __restrict__ y)
{
  for(int idx = blockIdx.x*256 + threadIdx.x; idx < NN*OC; idx += gridDim.x*256){
    int n = idx/OC, o = idx - n*OC;
    float v = bias[o];
    #pragma unroll
    for(int s=0;s<SL;s++) v += part[(size_t)s*NN*OC + idx];
    #pragma unroll
    for(int i=0;i<IC;i++) v += x[(size_t)n*IC+i]*root[i*OC+o];
    #pragma unroll
    for(int i=0;i<IC;i++) v += xbar[(size_t)n*IC+i]*b2[i*OC+o];
    y[idx] = fmaxf(v, 0.f);
  }
}

// ---------------- set2set (2 steps) + final MLP, one wave per graph ----------------
__global__ void k_s2s(const float* __restrict__ xg, const int* __restrict__ batch,
  const float* __restrict__ Wih, const float* __restrict__ Whh,
  const float* __restrict__ bih, const float* __restrict__ bhh,
  const float* __restrict__ l1W, const float* __restrict__ l1b,
  const float* __restrict__ l2W, const float* __restrict__ l2b,
  const float* __restrict__ lfW, const float* __restrict__ lfb,
  float* __restrict__ out)
{
  int g = blockIdx.x, lane = threadIdx.x;
  __shared__ float hs[16], cs[16], qs[32], gs[64], rs[16];
  int r0 = lowerb(batch, NN, g);
  int r1 = lowerb(batch, NN, g+1);
  if(lane<16){ hs[lane]=0.f; cs[lane]=0.f; }
  if(lane<32) qs[lane]=0.f;
  __syncthreads();
  for(int step=0; step<2; step++){
    float gate = bih[lane] + bhh[lane];
    for(int k=0;k<32;k++) gate += qs[k]*Wih[lane*32+k];
    for(int k=0;k<16;k++) gate += hs[k]*Whh[lane*16+k];
    gs[lane] = gate;
    __syncthreads();
    if(lane<16){
      float ig = 1.f/(1.f+expf(-gs[lane]));
      float fg = 1.f/(1.f+expf(-gs[lane+16]));
      float gg = tanhf(gs[lane+32]);
      float og = 1.f/(1.f+expf(-gs[lane+48]));
      float cn = fg*cs[lane] + ig*gg;
      cs[lane] = cn;
      hs[lane] = og*tanhf(cn);
    }
    __syncthreads();
    float m = -1e30f;
    for(int n=r0+lane; n<r1; n+=64){
      float e=0.f;
      for(int k=0;k<16;k++) e += xg[n*16+k]*hs[k];
      m = fmaxf(m, e);
    }
    for(int d=1; d<64; d<<=1) m = fmaxf(m, __shfl_xor(m, d));
    float ssum = 0.f;
    float racc[16];
    #pragma unroll
    for(int k=0;k<16;k++) racc[k]=0.f;
    for(int n=r0+lane; n<r1; n+=64){
      float e=0.f, xv[16];
      #pragma unroll
      for(int k=0;k<16;k++){ xv[k]=xg[n*16+k]; e += xv[k]*hs[k]; }
      float a = expf(e - m);
      ssum += a;
      #pragma unroll
      for(int k=0;k<16;k++) racc[k] += a*xv[k];
    }
    for(int d=1; d<64; d<<=1) ssum += __shfl_xor(ssum, d);
    #pragma unroll
    for(int k=0;k<16;k++)
      for(int d=1; d<64; d<<=1) racc[k] += __shfl_xor(racc[k], d);
    ssum = fmaxf(ssum, 1e-16f);
    if(lane==0){
      #pragma unroll
      for(int k=0;k<16;k++) rs[k] = racc[k]/ssum;
    }
    __syncthreads();
    if(lane<16){ qs[lane]=hs[lane]; qs[16+lane]=rs[lane]; }
    __syncthreads();
  }
  if(lane<16){
    float v = l1b[lane];
    for(int k=0;k<32;k++) v += qs[k]*l1W[k*16+lane];
    gs[lane] = fmaxf(v,0.f);
  }
  __syncthreads();
  if(lane<8){
    float v = l2b[lane];
    for(int k=0;k<16;k++) v += gs[k]*l2W[k*8+lane];
    gs[32+lane] = fmaxf(v,0.f);
  }
  __syncthreads();
  if(lane==0){
    float v = lfb[0];
    for(int k=0;k<8;k++) v += gs[32+k]*lfW[k];
    out[g] = v;
  }
}

extern "C" void kernel_launch(void* const* d_in, const int* in_sizes, int n_in,
                              void* d_out, int out_size, void* d_ws, size_t ws_size,
                              hipStream_t stream) {
  const float* x0   = (const float*)d_in[0];
  const int*   ei   = (const int*)d_in[1];
  const float* ea   = (const float*)d_in[2];
  const int*   batch= (const int*)d_in[3];
  const float* c1W1 = (const float*)d_in[4];  const float* c1b1 = (const float*)d_in[5];
  const float* c1W2 = (const float*)d_in[6];  const float* c1b2 = (const float*)d_in[7];
  const float* c1rt = (const float*)d_in[8];  const float* c1bs = (const float*)d_in[9];
  const float* c2W1 = (const float*)d_in[10]; const float* c2b1 = (const float*)d_in[11];
  const float* c2W2 = (const float*)d_in[12]; const float* c2b2 = (const float*)d_in[13];
  const float* c2rt = (const float*)d_in[14]; const float* c2bs = (const float*)d_in[15];
  const float* c3W1 = (const float*)d_in[16]; const float* c3b1 = (const float*)d_in[17];
  const float* c3W2 = (const float*)d_in[18]; const float* c3b2 = (const float*)d_in[19];
  const float* c3rt = (const float*)d_in[20]; const float* c3bs = (const float*)d_in[21];
  const float* Wih  = (const float*)d_in[22]; const float* Whh  = (const float*)d_in[23];
  const float* bih  = (const float*)d_in[24]; const float* bhh  = (const float*)d_in[25];
  const float* l1W  = (const float*)d_in[26]; const float* l1b  = (const float*)d_in[27];
  const float* l2W  = (const float*)d_in[28]; const float* l2b  = (const float*)d_in[29];
  const float* lfW  = (const float*)d_in[30]; const float* lfb  = (const float*)d_in[31];
  float* out = (float*)d_out;

  const int* src = ei;
  const int* tgt = ei + NE;

  // workspace carve
  char* w = (char*)d_ws;
  auto carve = [&](size_t bytes)->void*{ void* p = (void*)w; w += (bytes + 255) & ~(size_t)255; return p; };
  int*   row_start = (int*)carve((NN+1)*sizeof(int));
  int*   cur       = (int*)carve(NN*sizeof(int));
  int*   es_src    = (int*)carve(NE*sizeof(int));
  float* es_ea     = (float*)carve((size_t)NE*16*sizeof(float));
  float* xbar      = (float*)carve((size_t)NN*48*sizeof(float));
  float* y1   = (float*)carve((size_t)NN*48*sizeof(float));
  float* y2   = (float*)carve((size_t)NN*32*sizeof(float));
  float* y3   = (float*)carve((size_t)NN*16*sizeof(float));
  float* part = (float*)carve((size_t)16*NN*48*sizeof(float)); // up to 16 slices

  // ---- CSR by tgt (+ fused ea gather)
  hipMemsetAsync(cur, 0, NN*sizeof(int), stream);
  k_count<<<(NE+255)/256, 256, 0, stream>>>(tgt, cur);
  k_scan<<<1, 1024, 0, stream>>>(cur, row_start);
  hipMemsetAsync(cur, 0, NN*sizeof(int), stream);
  k_place<<<(NE+255)/256, 256, 0, stream>>>(src, tgt, ea, row_start, cur, es_src, es_ea);

  // ---- layer 1: IC=16 OC=48 | PLEN=64 KS=2 BN=8 G=2 PP=4 TI=4 | OQ=16 TO=3 | PF, EB=64 (8 slices)
  k_layer<16,48,64,2,8,4,4,16,3,true,64><<<(NN/8)*2, 256, 0, stream>>>(
      x0, es_ea, es_src, row_start, c1W1, c1b1, c1W2, part, xbar);
  k_epi<16,48,8><<<2048, 256, 0, stream>>>(part, x0, xbar, c1rt, c1b2, c1bs, y1);

  // ---- layer 2: IC=48 OC=32 | PLEN=32 KS=4 BN=8 G=2 PP=4 TI=6 | OQ=8 TO=4 | PF, EB=128 (16 slices)
  k_layer<48,32,32,4,8,4,6,8,4,true,128><<<(NN/8)*4, 256, 0, stream>>>(
      y1, es_ea, es_src, row_start, c2W1, c2b1, c2W2, part, xbar);
  k_epi<48,32,16><<<2048, 256, 0, stream>>>(part, y1, xbar, c2rt, c2b2, c2bs, y2);

  // ---- layer 3: IC=32 OC=16 | PLEN=64 KS=2 BN=4 G=1 PP=4 TI=8 | OQ=4 TO=4 | PF, EB=64 (8 slices)
  k_layer<32,16,64,2,4,4,8,4,4,true,64><<<(NN/4)*2, 256, 0, stream>>>(
      y2, es_ea, es_src, row_start, c3W1, c3b1, c3W2, part, xbar);
  k_epi<32,16,8><<<2048, 256, 0, stream>>>(part, y2, xbar, c3rt, c3b2, c3bs, y3);

  // ---- set2set + MLP head
  k_s2s<<<NG, 64, 0, stream>>>(y3, batch, Wih, Whh, bih, bhh, l1W, l1b, l2W, l2b, lfW, lfb, out);
}

// Round 13
// 691.863 us; speedup vs baseline: 1.3833x; 1.0457x over previous
//
#include <hip/hip_runtime.h>

#define NN 20000
#define NE 200000
#define NG 512

typedef float v2f __attribute__((ext_vector_type(2)));

__device__ __forceinline__ int lowerb(const int* a, int n, int v){
  int lo=0, hi=n;
  while(lo<hi){ int m=(lo+hi)>>1; if(a[m]<v) lo=m+1; else hi=m; }
  return lo;
}

// async global->LDS copy, 16B per lane. LDS dest must be linear in lane order
// (wave-uniform base + lane*16).
template<int AUX>
__device__ __forceinline__ void gload_lds16(const float4* g, float4* l){
  __builtin_amdgcn_global_load_lds(
    (const __attribute__((address_space(1))) void*)(g),
    (__attribute__((address_space(3))) void*)(l), 16, 0, AUX);
}

// ---------------- counting sort by tgt -> CSR ----------------
__global__ void k_count(const int* __restrict__ tgt, int* __restrict__ cnt){
  int e = blockIdx.x*blockDim.x + threadIdx.x;
  if(e<NE) atomicAdd(&cnt[tgt[e]], 1);
}

__global__ void k_scan(const int* __restrict__ cnt, int* __restrict__ row_start){
  __shared__ int part[1024];
  int t = threadIdx.x;
  const int CH = (NN + 1023)/1024; // 20
  int i0 = t*CH;
  int s = 0;
  for(int j=0;j<CH;j++){ int i=i0+j; if(i<NN) s += cnt[i]; }
  part[t] = s; __syncthreads();
  for(int d=1; d<1024; d<<=1){
    int v = (t>=d) ? part[t-d] : 0;
    __syncthreads();
    part[t] += v;
    __syncthreads();
  }
  int run = (t==0) ? 0 : part[t-1];
  for(int j=0;j<CH;j++){ int i=i0+j; if(i<NN){ row_start[i]=run; run += cnt[i]; } }
  if(t==0) row_start[NN] = part[1023];
}

// place edges in CSR order AND gather edge_attr to CSR order (fused)
__global__ void k_place(const int* __restrict__ src, const int* __restrict__ tgt,
                        const float* __restrict__ ea,
                        const int* __restrict__ row_start, int* __restrict__ cur,
                        int* __restrict__ es_src, float* __restrict__ es_ea){
  int e = blockIdx.x*blockDim.x + threadIdx.x;
  if(e>=NE) return;
  int n = tgt[e];
  int pos = row_start[n] + atomicAdd(&cur[n],1);
  es_src[pos] = src[e];
  const float4* s = (const float4*)ea + (size_t)e*4;
  float4* d = (float4*)es_ea + (size_t)pos*4;
  d[0]=s[0]; d[1]=s[1]; d[2]=s[2]; d[3]=s[3];
}

// ---------------- fused NNConv layer ----------------
// Round 13 = round-12 fused layer (best: 723us total) + two traffic/instruction cuts:
//  - Dead-S cross-wave combine (round-8-verified): waves 1-3 publish k-partials via
//    the dead S region; wave 0 sums and writes ONE part slice per split. part slices
//    8/16/8 -> 2/4/2: layer WRITE -33MB, epi reads -33MB, epi SL loop 4x shorter.
//  - Packed H-compute: each thread computes a column PAIR (v2f; W1 pair in 32 regs).
//    Halves H-phase iterations -> halves broadcast ds_read_b128 count + LDS writes.
//    Same accumulation order -> identical results.
// VGPR expected ~100-115 (<=128 is free: L2 LDS 48.5KB binds at 3 blocks = 12 waves;
// L1/L3 ~33KB -> 4 blocks = 16 waves = the 4/SIMD cap VGPR<=128 allows).
// All prior lessons intact: H/xbar fusion (round 12), PF scatter prefetch + W2-only
// ping-pong (rounds 2/8), S reads in-iteration (round 1), BN=8 for L1/L2 (round 7),
// no min-waves>3 (rounds 4/5), exact-multiple staging regions (no async-tail overlap).
// No-spill check: WRITE ~33MB, VGPR<=128, FETCH ~74MB.
template<int IC, int OC, int PLEN, int KS, int BN, int PP, int TI, int OQ, int TO, bool PF, int EB>
__launch_bounds__(256, 3)
__global__ void k_layer(const float* __restrict__ x_in, const float* __restrict__ es_ea,
                        const int* __restrict__ es_src, const int* __restrict__ row_start,
                        const float* __restrict__ W1, const float* __restrict__ b1,
                        const float* __restrict__ W2, float* __restrict__ part,
                        float* __restrict__ xbar_out)
{
  constexpr int K    = PLEN*IC;
  constexpr int XV   = IC/4;
  constexpr int NIW  = IC/TI;
  constexpr int NPW  = PLEN/PP;
  constexpr int G    = BN/4;
  constexpr int KQL  = 64/OQ;
  constexpr int TSPL = 4*KQL;
  constexpr int J    = (K/4)/TSPL;
  constexpr int NEA  = EB/64;            // ea staging chunks (EB*16/4/256)
  constexpr int NX4  = (EB*XV)/256;      // xs staging chunks (exact)
  constexpr int TI2  = TI/2;
  constexpr int NP   = TO/2;
  constexpr bool TODD = (TO & 1);
  constexpr int HP   = PLEN/2;           // column pairs per H-compute thread
  constexpr int EPB2 = 256/HP;           // edges per packed H-compute iteration
  static_assert(TI%2==0, "packed scatter needs even TI");
  static_assert(256%HP==0, "packed H-compute mapping");
  static_assert(EB%64==0, "ea region must be exact 256-f4 chunks");
  static_assert((EB*XV)%256==0, "xs region must be exact 256-f4 chunks");
  static_assert(EB*(PLEN+16+IC) <= BN*K, "staging alias fits in S");
  static_assert(NPW*NIW==64, "wave tile covers 64 lanes");
  static_assert(G*PP*TI <= 48, "spill-safe accumulator");
  static_assert(OQ*TO==OC && (K/4)%TSPL==0, "gemm tiling");
  static_assert(J%2==0, "ping-pong needs even J");
  static_assert(3*BN*OC <= BN*K, "combine area fits in dead S");

  __shared__ __align__(16) float S[BN*K];
  __shared__ int rs_s[BN+1], ro[BN+1];

  float* hb  = S;                        // EB*PLEN computed H slice
  float* eas = S + EB*PLEN;              // EB*16 staged edge_attr
  float* xs  = S + EB*(PLEN+16);         // EB*IC staged x[src]

  const int tid = threadIdx.x;
  const int wid = tid>>6, lane = tid&63;
  const int split = blockIdx.x % KS;
  const int nb = blockIdx.x / KS;
  const int n0 = nb*BN;

  if(tid<=BN) rs_s[tid] = row_start[n0+tid];
  __syncthreads();
  const int estart = rs_s[0], eend = rs_s[BN];

  const int pw = lane / NIW;
  const int iw = lane - pw*NIW;
  const int c2 = tid % HP, erow = tid / HP;

  // per-split W1 column PAIR + bias pair (hoisted; coalesced loads)
  v2f w1cp[16];
  const v2f b1cp = *(const v2f*)&b1[split*PLEN + 2*c2];
  #pragma unroll
  for(int i=0;i<16;i++) w1cp[i] = *(const v2f*)&W1[i*128 + split*PLEN + 2*c2];

  v2f acc2[G][PP][TI2];
  v2f xsum2[G][TI2];
  #pragma unroll
  for(int g=0;g<G;g++){
    #pragma unroll
    for(int p=0;p<PP;p++)
      #pragma unroll
      for(int u=0;u<TI2;u++) acc2[g][p][u]=v2f{0.f,0.f};
    #pragma unroll
    for(int u=0;u<TI2;u++) xsum2[g][u]=v2f{0.f,0.f};
  }

  const float4* EA4 = (const float4*)es_ea;
  const float4* x4  = (const float4*)x_in;

  for(int bstart=estart; bstart<eend; bstart+=EB){
    const int ebc = min(EB, eend-bstart);
    if(tid<=BN){ int v = rs_s[tid]-bstart; ro[tid] = min(max(v,0), ebc); }
    const int ea_lim = ebc*4, xs_lim = ebc*XV;
    // pre-load gather indices (independent loads, issued together)
    int sn_r[NX4];
    #pragma unroll
    for(int c=0;c<NX4;c++){
      int jc = min(tid + c*256, xs_lim-1);
      sn_r[c] = es_src[bstart + jc/XV];
    }
    // async edge_attr -> eas (CSR-linear source)
    #pragma unroll
    for(int c=0;c<NEA;c++){
      int j = tid + c*256;
      int jc = min(j, ea_lim-1);
      gload_lds16<0>(EA4 + (size_t)bstart*4 + jc, ((float4*)eas) + j);
    }
    // async x[src] -> xs
    #pragma unroll
    for(int c=0;c<NX4;c++){
      int j = tid + c*256;
      int jc = min(j, xs_lim-1);
      int q = jc - (jc/XV)*XV;
      gload_lds16<0>(x4 + (size_t)sn_r[c]*XV + q, ((float4*)xs) + j);
    }
    __syncthreads();   // drains vmcnt (global_load_lds tracked there)

    // ---- compute H slice (packed column pairs): h[e][2c2..2c2+1] ----
    for(int ec = erow; ec < ebc; ec += EPB2){
      v2f h = b1cp;
      #pragma unroll
      for(int q=0;q<4;q++){
        float4 a = *(const float4*)&eas[ec*16 + 4*q];   // broadcast within group
        h += v2f{a.x,a.x}*w1cp[4*q+0];
        h += v2f{a.y,a.y}*w1cp[4*q+1];
        h += v2f{a.z,a.z}*w1cp[4*q+2];
        h += v2f{a.w,a.w}*w1cp[4*q+3];
      }
      h[0] = fmaxf(h[0],0.f); h[1] = fmaxf(h[1],0.f);
      *(v2f*)&hb[ec*PLEN + 2*c2] = h;
    }
    __syncthreads();

    // ---- wave-private scatter (only the owning wave touches its nodes' edges) ----
    if constexpr (PF){
      #pragma unroll
      for(int g=0; g<G; g++){
        const int nl = wid*G + g;
        const int a = ro[nl], b = ro[nl+1];
        if(a>=b) continue;
        float hv[PP]; v2f xv2[TI2];
        #pragma unroll
        for(int p=0;p<PP;p++) hv[p] = hb[a*PLEN + pw*PP + p];
        #pragma unroll
        for(int u=0;u<TI2;u++) xv2[u] = *(const v2f*)&xs[a*IC + iw*TI + 2*u];
        for(int e=a; e<b; e++){
          float hn[PP]; v2f xn2[TI2];
          if(e+1<b){
            #pragma unroll
            for(int p=0;p<PP;p++) hn[p] = hb[(e+1)*PLEN + pw*PP + p];
            #pragma unroll
            for(int u=0;u<TI2;u++) xn2[u] = *(const v2f*)&xs[(e+1)*IC + iw*TI + 2*u];
          }
          #pragma unroll
          for(int p=0;p<PP;p++){
            v2f h2 = v2f{hv[p], hv[p]};
            #pragma unroll
            for(int u=0;u<TI2;u++) acc2[g][p][u] += h2*xv2[u];
          }
          #pragma unroll
          for(int u=0;u<TI2;u++) xsum2[g][u] += xv2[u];
          #pragma unroll
          for(int p=0;p<PP;p++) hv[p]=hn[p];
          #pragma unroll
          for(int u=0;u<TI2;u++) xv2[u]=xn2[u];
        }
      }
    } else {
      #pragma unroll
      for(int g=0; g<G; g++){
        const int nl = wid*G + g;
        const int a = ro[nl], b = ro[nl+1];
        for(int e=a; e<b; e++){
          float hv[PP];
          #pragma unroll
          for(int p=0;p<PP;p++) hv[p] = hb[e*PLEN + pw*PP + p];
          v2f xv2[TI2];
          #pragma unroll
          for(int u=0;u<TI2;u++) xv2[u] = *(const v2f*)&xs[e*IC + iw*TI + 2*u];
          #pragma unroll
          for(int p=0;p<PP;p++){
            v2f h2 = v2f{hv[p], hv[p]};
            #pragma unroll
            for(int u=0;u<TI2;u++) acc2[g][p][u] += h2*xv2[u];
          }
          #pragma unroll
          for(int u=0;u<TI2;u++) xsum2[g][u] += xv2[u];
        }
      }
    }
    __syncthreads();
  }

  // xbar write (split 0 only; pw==0 lanes hold the full iw-slice sums)
  if(split==0 && pw==0){
    #pragma unroll
    for(int g=0;g<G;g++){
      const int nl = wid*G + g;
      const float dv = 1.f/fmaxf((float)(rs_s[nl+1]-rs_s[nl]), 1.f);
      #pragma unroll
      for(int u=0;u<TI2;u++){
        v2f r = xsum2[g][u]*v2f{dv,dv};
        *(v2f*)&xbar_out[(size_t)(n0+nl)*IC + iw*TI + 2*u] = r;
      }
    }
  }

  // dump scaled S (staging area dead)
  #pragma unroll
  for(int g=0; g<G; g++){
    const int nl = wid*G + g;
    const float dv = 1.f/fmaxf((float)(rs_s[nl+1]-rs_s[nl]), 1.f);
    const v2f dv2 = v2f{dv, dv};
    #pragma unroll
    for(int p=0;p<PP;p++)
      #pragma unroll
      for(int u=0;u<TI2;u++)
        *(v2f*)&S[(nl*PLEN + pw*PP + p)*IC + iw*TI + 2*u] = acc2[g][p][u]*dv2;
  }

  // ---- GEMM: slice[n][o] partial over this wave's k-range; coalesced W2 ----
  const int oq  = lane % OQ;
  const int kql = lane / OQ;
  const int o0  = oq*TO;
  const float* W2b = W2 + (size_t)split*K*OC + o0;

  auto LOADW = [&](int j, v2f (&wv2)[4][NP], float (&wvs)[4]){
    const int k4 = j*TSPL + wid*KQL + kql;
    #pragma unroll
    for(int r=0;r<4;r++){
      const float* wr = W2b + (size_t)(4*k4+r)*OC;
      if constexpr (TO==4){
        float4 a=*(const float4*)wr;
        wv2[r][0]=v2f{a.x,a.y}; wv2[r][1]=v2f{a.z,a.w};
      } else if constexpr (TO==3){
        wv2[r][0]=v2f{wr[0],wr[1]}; wvs[r]=wr[2];
      } else {
        float2 a=*(const float2*)wr;
        wv2[r][0]=v2f{a.x,a.y};
      }
    }
  };

  v2f outp2[BN][NP];
  float outs[BN];
  #pragma unroll
  for(int n=0;n<BN;n++){
    #pragma unroll
    for(int t=0;t<NP;t++) outp2[n][t]=v2f{0.f,0.f};
    outs[n]=0.f;
  }

  v2f wvA[4][NP], wvB[4][NP];
  float wsA[4], wsB[4];
  LOADW(0, wvA, wsA);     // W2 j=0 in flight across the barrier (independent of S)
  __syncthreads();        // S visible to all waves

  #pragma unroll 1
  for(int j=0;j<J;j+=2){
    LOADW(j+1, wvB, wsB); // prefetch while FMAs on wvA run
    {
      const int k4 = j*TSPL + wid*KQL + kql;
      #pragma unroll
      for(int n=0;n<BN;n++){
        float4 sv = *(const float4*)&S[n*K + 4*k4];
        v2f s0=v2f{sv.x,sv.x}, s1=v2f{sv.y,sv.y}, s2=v2f{sv.z,sv.z}, s3=v2f{sv.w,sv.w};
        #pragma unroll
        for(int t=0;t<NP;t++)
          outp2[n][t] += s0*wvA[0][t] + s1*wvA[1][t] + s2*wvA[2][t] + s3*wvA[3][t];
        if constexpr (TODD)
          outs[n] += sv.x*wsA[0] + sv.y*wsA[1] + sv.z*wsA[2] + sv.w*wsA[3];
      }
    }
    if(j+2<J) LOADW(j+2, wvA, wsA);   // prefetch while FMAs on wvB run
    {
      const int k4 = (j+1)*TSPL + wid*KQL + kql;
      #pragma unroll
      for(int n=0;n<BN;n++){
        float4 sv = *(const float4*)&S[n*K + 4*k4];
        v2f s0=v2f{sv.x,sv.x}, s1=v2f{sv.y,sv.y}, s2=v2f{sv.z,sv.z}, s3=v2f{sv.w,sv.w};
        #pragma unroll
        for(int t=0;t<NP;t++)
          outp2[n][t] += s0*wvB[0][t] + s1*wvB[1][t] + s2*wvB[2][t] + s3*wvB[3][t];
        if constexpr (TODD)
          outs[n] += sv.x*wsB[0] + sv.y*wsB[1] + sv.z*wsB[2] + sv.w*wsB[3];
      }
    }
  }

  // intra-wave reduce over kql lanes (masks OQ..32)
  #pragma unroll
  for(int m=OQ; m<64; m<<=1)
    #pragma unroll
    for(int n=0;n<BN;n++){
      #pragma unroll
      for(int t=0;t<NP;t++){
        outp2[n][t][0] += __shfl_xor(outp2[n][t][0], m, 64);
        outp2[n][t][1] += __shfl_xor(outp2[n][t][1], m, 64);
      }
      if constexpr (TODD) outs[n] += __shfl_xor(outs[n], m, 64);
    }

  // cross-wave combine through dead S: ONE part slice per split (round-8-verified)
  __syncthreads();   // all GEMM S-reads complete
  if(wid>0 && kql==0){
    #pragma unroll
    for(int n=0;n<BN;n++){
      #pragma unroll
      for(int t=0;t<NP;t++){
        S[((wid-1)*BN+n)*OC + o0 + 2*t]   = outp2[n][t][0];
        S[((wid-1)*BN+n)*OC + o0 + 2*t+1] = outp2[n][t][1];
      }
      if constexpr (TODD) S[((wid-1)*BN+n)*OC + o0 + TO-1] = outs[n];
    }
  }
  __syncthreads();
  if(wid==0 && kql==0){
    float* slice = part + (size_t)split*NN*OC;
    #pragma unroll
    for(int n=0;n<BN;n++){
      float tmp[TO];
      #pragma unroll
      for(int t=0;t<NP;t++){ tmp[2*t]=outp2[n][t][0]; tmp[2*t+1]=outp2[n][t][1]; }
      if constexpr (TODD) tmp[TO-1]=outs[n];
      #pragma unroll
      for(int w2=0;w2<3;w2++)
        #pragma unroll
        for(int t=0;t<TO;t++) tmp[t] += S[(w2*BN+n)*OC + o0 + t];
      float* dst = slice + (size_t)(n0+n)*OC + o0;
      if constexpr (TO==4){
        *(float4*)dst = make_float4(tmp[0],tmp[1],tmp[2],tmp[3]);
      } else if constexpr (TO==3){
        dst[0]=tmp[0]; dst[1]=tmp[1]; dst[2]=tmp[2];
      } else {
        *(float2*)dst = make_float2(tmp[0],tmp[1]);
      }
    }
  }
}

// ---------------- epilogue: y = relu(sum_s part[s] + x@root + xbar@b2 + bias) ----------------
// Grid-stride (round-8 aux win); SL = KS now (combine cut slices 4x).
template<int IC, int OC, int SL>
__global__ void k_epi(const float* __restrict__ part, const float* __restrict__ x,
                      const float* __restrict__ xbar,
                      const float* __restrict__ root, const float* __restrict__ b2,
                      const float* __restrict__ bias, float* __restrict__ y)
{
  for(int idx = blockIdx.x*256 + threadIdx.x; idx < NN*OC; idx += gridDim.x*256){
    int n = idx/OC, o = idx - n*OC;
    float v = bias[o];
    #pragma unroll
    for(int s=0;s<SL;s++) v += part[(size_t)s*NN*OC + idx];
    #pragma unroll
    for(int i=0;i<IC;i++) v += x[(size_t)n*IC+i]*root[i*OC+o];
    #pragma unroll
    for(int i=0;i<IC;i++) v += xbar[(size_t)n*IC+i]*b2[i*OC+o];
    y[idx] = fmaxf(v, 0.f);
  }
}

// ---------------- set2set (2 steps) + final MLP, one wave per graph ----------------
__global__ void k_s2s(const float* __restrict__ xg, const int* __restrict__ batch,
  const float* __restrict__ Wih, const float* __restrict__ Whh,
  const float* __restrict__ bih, const float* __restrict__ bhh,
  const float* __restrict__ l1W, const float* __restrict__ l1b,
  const float* __restrict__ l2W, const float* __restrict__ l2b,
  const float* __restrict__ lfW, const float* __restrict__ lfb,
  float* __restrict__ out)
{
  int g = blockIdx.x, lane = threadIdx.x;
  __shared__ float hs[16], cs[16], qs[32], gs[64], rs[16];
  int r0 = lowerb(batch, NN, g);
  int r1 = lowerb(batch, NN, g+1);
  if(lane<16){ hs[lane]=0.f; cs[lane]=0.f; }
  if(lane<32) qs[lane]=0.f;
  __syncthreads();
  for(int step=0; step<2; step++){
    float gate = bih[lane] + bhh[lane];
    for(int k=0;k<32;k++) gate += qs[k]*Wih[lane*32+k];
    for(int k=0;k<16;k++) gate += hs[k]*Whh[lane*16+k];
    gs[lane] = gate;
    __syncthreads();
    if(lane<16){
      float ig = 1.f/(1.f+expf(-gs[lane]));
      float fg = 1.f/(1.f+expf(-gs[lane+16]));
      float gg = tanhf(gs[lane+32]);
      float og = 1.f/(1.f+expf(-gs[lane+48]));
      float cn = fg*cs[lane] + ig*gg;
      cs[lane] = cn;
      hs[lane] = og*tanhf(cn);
    }
    __syncthreads();
    float m = -1e30f;
    for(int n=r0+lane; n<r1; n+=64){
      float e=0.f;
      for(int k=0;k<16;k++) e += xg[n*16+k]*hs[k];
      m = fmaxf(m, e);
    }
    for(int d=1; d<64; d<<=1) m = fmaxf(m, __shfl_xor(m, d));
    float ssum = 0.f;
    float racc[16];
    #pragma unroll
    for(int k=0;k<16;k++) racc[k]=0.f;
    for(int n=r0+lane; n<r1; n+=64){
      float e=0.f, xv[16];
      #pragma unroll
      for(int k=0;k<16;k++){ xv[k]=xg[n*16+k]; e += xv[k]*hs[k]; }
      float a = expf(e - m);
      ssum += a;
      #pragma unroll
      for(int k=0;k<16;k++) racc[k] += a*xv[k];
    }
    for(int d=1; d<64; d<<=1) ssum += __shfl_xor(ssum, d);
    #pragma unroll
    for(int k=0;k<16;k++)
      for(int d=1; d<64; d<<=1) racc[k] += __shfl_xor(racc[k], d);
    ssum = fmaxf(ssum, 1e-16f);
    if(lane==0){
      #pragma unroll
      for(int k=0;k<16;k++) rs[k] = racc[k]/ssum;
    }
    __syncthreads();
    if(lane<16){ qs[lane]=hs[lane]; qs[16+lane]=rs[lane]; }
    __syncthreads();
  }
  if(lane<16){
    float v = l1b[lane];
    for(int k=0;k<32;k++) v += qs[k]*l1W[k*16+lane];
    gs[lane] = fmaxf(v,0.f);
  }
  __syncthreads();
  if(lane<8){
    float v = l2b[lane];
    for(int k=0;k<16;k++) v += gs[k]*l2W[k*8+lane];
    gs[32+lane] = fmaxf(v,0.f);
  }
  __syncthreads();
  if(lane==0){
    float v = lfb[0];
    for(int k=0;k<8;k++) v += gs[32+k]*lfW[k];
    out[g] = v;
  }
}

extern "C" void kernel_launch(void* const* d_in, const int* in_sizes, int n_in,
                              void* d_out, int out_size, void* d_ws, size_t ws_size,
                              hipStream_t stream) {
  const float* x0   = (const float*)d_in[0];
  const int*   ei   = (const int*)d_in[1];
  const float* ea   = (const float*)d_in[2];
  const int*   batch= (const int*)d_in[3];
  const float* c1W1 = (const float*)d_in[4];  const float* c1b1 = (const float*)d_in[5];
  const float* c1W2 = (const float*)d_in[6];  const float* c1b2 = (const float*)d_in[7];
  const float* c1rt = (const float*)d_in[8];  const float* c1bs = (const float*)d_in[9];
  const float* c2W1 = (const float*)d_in[10]; const float* c2b1 = (const float*)d_in[11];
  const float* c2W2 = (const float*)d_in[12]; const float* c2b2 = (const float*)d_in[13];
  const float* c2rt = (const float*)d_in[14]; const float* c2bs = (const float*)d_in[15];
  const float* c3W1 = (const float*)d_in[16]; const float* c3b1 = (const float*)d_in[17];
  const float* c3W2 = (const float*)d_in[18]; const float* c3b2 = (const float*)d_in[19];
  const float* c3rt = (const float*)d_in[20]; const float* c3bs = (const float*)d_in[21];
  const float* Wih  = (const float*)d_in[22]; const float* Whh  = (const float*)d_in[23];
  const float* bih  = (const float*)d_in[24]; const float* bhh  = (const float*)d_in[25];
  const float* l1W  = (const float*)d_in[26]; const float* l1b  = (const float*)d_in[27];
  const float* l2W  = (const float*)d_in[28]; const float* l2b  = (const float*)d_in[29];
  const float* lfW  = (const float*)d_in[30]; const float* lfb  = (const float*)d_in[31];
  float* out = (float*)d_out;

  const int* src = ei;
  const int* tgt = ei + NE;

  // workspace carve
  char* w = (char*)d_ws;
  auto carve = [&](size_t bytes)->void*{ void* p = (void*)w; w += (bytes + 255) & ~(size_t)255; return p; };
  int*   row_start = (int*)carve((NN+1)*sizeof(int));
  int*   cur       = (int*)carve(NN*sizeof(int));
  int*   es_src    = (int*)carve(NE*sizeof(int));
  float* es_ea     = (float*)carve((size_t)NE*16*sizeof(float));
  float* xbar      = (float*)carve((size_t)NN*48*sizeof(float));
  float* y1   = (float*)carve((size_t)NN*48*sizeof(float));
  float* y2   = (float*)carve((size_t)NN*32*sizeof(float));
  float* y3   = (float*)carve((size_t)NN*16*sizeof(float));
  float* part = (float*)carve((size_t)16*NN*48*sizeof(float)); // up to 16 slices

  // ---- CSR by tgt (+ fused ea gather)
  hipMemsetAsync(cur, 0, NN*sizeof(int), stream);
  k_count<<<(NE+255)/256, 256, 0, stream>>>(tgt, cur);
  k_scan<<<1, 1024, 0, stream>>>(cur, row_start);
  hipMemsetAsync(cur, 0, NN*sizeof(int), stream);
  k_place<<<(NE+255)/256, 256, 0, stream>>>(src, tgt, ea, row_start, cur, es_src, es_ea);

  // ---- layer 1: IC=16 OC=48 | PLEN=64 KS=2 BN=8 G=2 PP=4 TI=4 | OQ=16 TO=3 | PF, EB=64 (2 slices)
  k_layer<16,48,64,2,8,4,4,16,3,true,64><<<(NN/8)*2, 256, 0, stream>>>(
      x0, es_ea, es_src, row_start, c1W1, c1b1, c1W2, part, xbar);
  k_epi<16,48,2><<<2048, 256, 0, stream>>>(part, x0, xbar, c1rt, c1b2, c1bs, y1);

  // ---- layer 2: IC=48 OC=32 | PLEN=32 KS=4 BN=8 G=2 PP=4 TI=6 | OQ=8 TO=4 | PF, EB=128 (4 slices)
  k_layer<48,32,32,4,8,4,6,8,4,true,128><<<(NN/8)*4, 256, 0, stream>>>(
      y1, es_ea, es_src, row_start, c2W1, c2b1, c2W2, part, xbar);
  k_epi<48,32,4><<<2048, 256, 0, stream>>>(part, y1, xbar, c2rt, c2b2, c2bs, y2);

  // ---- layer 3: IC=32 OC=16 | PLEN=64 KS=2 BN=4 G=1 PP=4 TI=8 | OQ=4 TO=4 | PF, EB=64 (2 slices)
  k_layer<32,16,64,2,4,4,8,4,4,true,64><<<(NN/4)*2, 256, 0, stream>>>(
      y2, es_ea, es_src, row_start, c3W1, c3b1, c3W2, part, xbar);
  k_epi<32,16,2><<<2048, 256, 0, stream>>>(part, y2, xbar, c3rt, c3b2, c3bs, y3);

  // ---- set2set + MLP head
  k_s2s<<<NG, 64, 0, stream>>>(y3, batch, Wih, Whh, bih, bhh, l1W, l1b, l2W, l2b, lfW, lfb, out);
}